// Round 10
// baseline (257.070 us; speedup 1.0000x reference)
//
#include <hip/hip_runtime.h>

// DMV inside (log2-space), one block per batch item, 512 threads = 128 groups of 4.
//  - FIXED group<->cell mapping: group g<64 = right-direction head h=g (cell
//    (h,h+w)); group 64+h = left head h (cell (h,h-w)). Exactly 128 head-slots.
//    Active right iff h+w<=nl-1, left iff w<=h<=nl-1 (monotone: once inactive,
//    never active again -> register caches never go stale).
//  - REGISTER-CACHED self-streams: element k of the cell's own F-row lives at
//    (lane k&3, slot k>>2) in fReg[]; I-width v at (lane (v-1)&3, slot (v-1)>>2)
//    in iReg[]. All slot indices compile-time (template NJ + uniform branch),
//    so arrays stay in VGPRs (rule: runtime-indexed arrays -> scratch, R8).
//    Phase-A own-F reads and phase-B I-reads cost ZERO LDS ops; sI is DELETED
//    (nothing reads it) -> DS ops/step 4NJ+2 -> 2NJ+1, LDS 37.9K -> ~20K.
//    Rationale: R9 DS-pipe occupancy (~4NJ b32 x 5.8cyc, one pipe/CU) ~58us
//    exceeded VALU 43us -> LDS pipe was the near-critical resource.
//  - F stays in LDS (other groups read row e in phase A, column e in phase B).
//  - Diagonal (width-0) = stNC param selected at endpoints; CR/CL folded (ghm).
//  - Fused A+B, one barrier per width. template<NJ=ceil(w/4)> dispatch.
//  - Masked lanes may read unwritten LDS (could be NaN): every such value is
//    replaced via (k<w)?v:NEGV BEFORE any reduce -> NaN never propagates.
//  - 4-lane DPP reduce (quad_perm xor1/xor2). 4 blocks/CU via launch_bounds
//    (512,8) -> VGPR<=64 enforced; spill sentinel = WRITE_SIZE (R8 lesson).
//  - Load balance: counting-sort + quartile snake (R7).

#define NEGV   -1000000000.0f
#define NMAX   64
#define LDS_S  69
#define BLOCK  512

#if __has_builtin(__builtin_amdgcn_exp2f)
#define EXP2F(x) __builtin_amdgcn_exp2f(x)
#else
#define EXP2F(x) __expf((x) * 0.6931471805599453f)
#endif
#if __has_builtin(__builtin_amdgcn_logf)
#define LOG2F(x) __builtin_amdgcn_logf(x)
#else
#define LOG2F(x) (__logf(x) * 1.4426950408889634f)
#endif
#define LOG2E 1.4426950408889634f
#define LN2   0.6931471805599453f

template<int CTRL>
__device__ __forceinline__ float dppf(float v) {
    return __int_as_float(__builtin_amdgcn_update_dpp(
        0, __float_as_int(v), CTRL, 0xF, 0xF, true));
}
__device__ __forceinline__ float grp4_max(float m) {
    m = fmaxf(m, dppf<0xB1>(m));    // quad_perm xor 1
    m = fmaxf(m, dppf<0x4E>(m));    // quad_perm xor 2
    return m;
}
__device__ __forceinline__ float grp4_sum(float s) {
    s += dppf<0xB1>(s);
    s += dppf<0x4E>(s);
    return s;
}

__device__ __forceinline__ void lse_merge(float& m, float& s, float mo, float so) {
    float mn = fmaxf(m, mo);
    s = s * EXP2F(m - mn) + so * EXP2F(mo - mn);
    m = mn;
}

// ---- pre-kernel: counting sort by length (descending) + quartile-snake map ----
__global__ void order_kernel(const int* __restrict__ len_arr,
                             int* __restrict__ blk2item, int B)
{
    __shared__ int hist[33];
    __shared__ int base[33];
    const int tid = threadIdx.x;
    if (tid < 33) hist[tid] = 0;
    __syncthreads();
    int bin = 0;
    if (tid < B) {
        bin = 64 - len_arr[tid];          // 0 = longest
        atomicAdd(&hist[bin], 1);
    }
    __syncthreads();
    if (tid == 0) {
        int acc = 0;
        for (int i = 0; i < 33; ++i) { base[i] = acc; acc += hist[i]; }
    }
    __syncthreads();
    if (tid < B) {
        int rank = atomicAdd(&base[bin], 1);   // sorted-descending rank
        int j;
        if ((B & 255) == 0) {                   // snake across quartile stripes
            int q = rank >> 8, pos = rank & 255;
            j = (q & 1) ? ((q << 8) + 255 - pos) : ((q << 8) + pos);
        } else {
            j = rank;
        }
        blk2item[j] = tid;
    }
}

// Fused A+B step for this group's (fixed) cell. NJ = ceil(w/4) compile-time.
template<int NJ>
__device__ __forceinline__ void dmv_step(
    const int w, const int nl, const int gid, const int lg,
    float (&fReg)[16], float (&iReg)[16],
    float* __restrict__ sF,
    const float* __restrict__ goNC, const float* __restrict__ goHM,
    const float* __restrict__ stHC, const float* __restrict__ stNC,
    const int* __restrict__ th_s, const float* __restrict__ trans_param)
{
    const bool isR = gid < 64;
    const int  h   = isR ? gid : (gid - 64);
    const bool act = isR ? (h + w <= nl - 1) : (w <= h && h <= nl - 1);
    if (!act) return;
    const int  sd  = isR ? 1 : 0;
    const int  dir = isR ? 1 : -1;
    const int  e   = isR ? (h + w) : (h - w);

    // ---- phase A: I[h][e] = tr + lse_k( C_own(k) + go + F_other(k) ) ----
    const float tr  = trans_param[(th_s[h] * NMAX + th_s[e]) * 2 + sd] * LOG2E;
    const float gnc = goNC[sd * NMAX + h];
    const float ghm = goHM[sd * NMAX + h];
    const float dcO = stNC[(sd ^ 1) * NMAX + e];
    const int   oC  = e * LDS_S + h + dir;     // other F row e, elem [dir*k]
    float x[NJ];
    #pragma unroll
    for (int j = 0; j < NJ; ++j) {
        const int k = lg + 4 * j;
        if (j == NJ - 1) {                     // endpoint slot only
            const int kc = (k < w - 1) ? k : (w - 1);   // address clamp
            float vC = (k == w - 1) ? dcO : sF[oC + dir * kc];
            float base = (k == 0) ? gnc : (fReg[j] + ghm);
            float v = base + vC;
            x[j] = (k < w) ? v : NEGV;         // masks any garbage/NaN
        } else {                               // k < w-1 guaranteed
            float vC = sF[oC + dir * k];
            float base = (j == 0 && k == 0) ? gnc : (fReg[j] + ghm);
            x[j] = base + vC;
        }
    }
    float mA = x[0];
    #pragma unroll
    for (int j = 1; j < NJ; ++j) mA = fmaxf(mA, x[j]);
    mA = grp4_max(mA);
    float sA = 0.f;
    #pragma unroll
    for (int j = 0; j < NJ; ++j) sA += EXP2F(x[j] - mA);
    sA = grp4_sum(sA);
    const float ir = mA + LOG2F(sA) + tr;      // group-uniform after DPP
    // store I-width w: lane (w-1)&3, slot (w-1)>>2 == NJ-1 (static)
    if (lg == ((w - 1) & 3)) iReg[NJ - 1] = ir;

    // ---- phase B: F[h][e] = lse_k( I_own(k+1) + F_col(k+1) ) + st_hc ----
    const float dcN = stNC[sd * NMAX + e];
    const float sth = stHC[sd * NMAX + h];
    const int   oF2 = (h + dir) * LDS_S + e;   // elem [dir*k*LDS_S]
    float y[NJ];
    #pragma unroll
    for (int j = 0; j < NJ; ++j) {
        const int k = lg + 4 * j;
        if (j == NJ - 1) {
            const int kc = (k < w - 1) ? k : (w - 1);   // address clamp
            float v1 = iReg[j];                         // width k+1 (ir if k==w-1)
            float v2 = (k == w - 1) ? dcN : sF[oF2 + dir * kc * LDS_S];
            float v  = v1 + v2;
            y[j] = (k < w) ? v : NEGV;
        } else {
            y[j] = iReg[j] + sF[oF2 + dir * k * LDS_S];
        }
    }
    float mB = y[0];
    #pragma unroll
    for (int j = 1; j < NJ; ++j) mB = fmaxf(mB, y[j]);
    mB = grp4_max(mB);
    float sB = 0.f;
    #pragma unroll
    for (int j = 0; j < NJ; ++j) sB += EXP2F(y[j] - mB);
    sB = grp4_sum(sB);
    const float f = mB + LOG2F(sB) + sth;      // group-uniform after DPP

    if (lg == 0) sF[h * LDS_S + e] = f;        // publish for other groups
    // store F-width w: lane w&3, slot w>>2 (== NJ-1, or NJ when w==4*NJ)
    if constexpr (NJ < 16) {
        if (w == 4 * NJ) { if (lg == 0) fReg[NJ] = f; }
        else             { if (lg == (w & 3)) fReg[NJ - 1] = f; }
    } else {
        if (lg == (w & 3)) fReg[NJ - 1] = f;   // w in {61,62,63}; w==64 impossible
    }
}

__global__ __launch_bounds__(BLOCK, 8)
void dmv_inside_kernel(const int* __restrict__ tag,
                       const int* __restrict__ len_arr,
                       const float* __restrict__ root_param,
                       const float* __restrict__ trans_param,
                       const float* __restrict__ dec_param,
                       const int* __restrict__ blk2item,
                       float* __restrict__ out)
{
    __shared__ float sF[NMAX * LDS_S];     // FR upper / FL lower triangle
    __shared__ float goNC[2 * NMAX];       // [0]=L, [1]=R (log2-scaled)
    __shared__ float goHM[2 * NMAX];       // go_hc - st_hc
    __shared__ float stHC[2 * NMAX];
    __shared__ float stNC[2 * NMAX];       // the "diagonal" of F
    __shared__ float root_s[NMAX];
    __shared__ int   th_s[NMAX];

    const int b   = blk2item[blockIdx.x];  // balanced assignment
    const int tid = threadIdx.x;
    const int nl  = len_arr[b];            // 32..64; output depends only on [0,nl)

    if (tid < NMAX) {
        int t = tag[b * NMAX + tid];
        th_s[tid] = t;
        const float* d = dec_param + t * 8;   // [dir][val][dec], L=0 R=1
        goNC[0 * NMAX + tid] = d[0] * LOG2E;
        stNC[0 * NMAX + tid] = d[1] * LOG2E;
        goHM[0 * NMAX + tid] = (d[2] - d[3]) * LOG2E;
        stHC[0 * NMAX + tid] = d[3] * LOG2E;
        goNC[1 * NMAX + tid] = d[4] * LOG2E;
        stNC[1 * NMAX + tid] = d[5] * LOG2E;
        goHM[1 * NMAX + tid] = (d[6] - d[7]) * LOG2E;
        stHC[1 * NMAX + tid] = d[7] * LOG2E;
        root_s[tid]          = root_param[t] * LOG2E;
    }
    __syncthreads();

    const int gid = tid >> 2;      // 0..127: fixed head slot (0..63 R, 64..127 L)
    const int lg  = tid & 3;

    float fReg[16], iReg[16];
    #pragma unroll
    for (int i = 0; i < 16; ++i) { fReg[i] = NEGV; iReg[i] = NEGV; }

    for (int w = 1; w < nl; ++w) {
        switch ((w - 1) >> 2) {    // block-uniform dispatch, NJ=ceil(w/4)
        case  0: dmv_step< 1>(w, nl, gid, lg, fReg, iReg, sF, goNC, goHM, stHC, stNC, th_s, trans_param); break;
        case  1: dmv_step< 2>(w, nl, gid, lg, fReg, iReg, sF, goNC, goHM, stHC, stNC, th_s, trans_param); break;
        case  2: dmv_step< 3>(w, nl, gid, lg, fReg, iReg, sF, goNC, goHM, stHC, stNC, th_s, trans_param); break;
        case  3: dmv_step< 4>(w, nl, gid, lg, fReg, iReg, sF, goNC, goHM, stHC, stNC, th_s, trans_param); break;
        case  4: dmv_step< 5>(w, nl, gid, lg, fReg, iReg, sF, goNC, goHM, stHC, stNC, th_s, trans_param); break;
        case  5: dmv_step< 6>(w, nl, gid, lg, fReg, iReg, sF, goNC, goHM, stHC, stNC, th_s, trans_param); break;
        case  6: dmv_step< 7>(w, nl, gid, lg, fReg, iReg, sF, goNC, goHM, stHC, stNC, th_s, trans_param); break;
        case  7: dmv_step< 8>(w, nl, gid, lg, fReg, iReg, sF, goNC, goHM, stHC, stNC, th_s, trans_param); break;
        case  8: dmv_step< 9>(w, nl, gid, lg, fReg, iReg, sF, goNC, goHM, stHC, stNC, th_s, trans_param); break;
        case  9: dmv_step<10>(w, nl, gid, lg, fReg, iReg, sF, goNC, goHM, stHC, stNC, th_s, trans_param); break;
        case 10: dmv_step<11>(w, nl, gid, lg, fReg, iReg, sF, goNC, goHM, stHC, stNC, th_s, trans_param); break;
        case 11: dmv_step<12>(w, nl, gid, lg, fReg, iReg, sF, goNC, goHM, stHC, stNC, th_s, trans_param); break;
        case 12: dmv_step<13>(w, nl, gid, lg, fReg, iReg, sF, goNC, goHM, stHC, stNC, th_s, trans_param); break;
        case 13: dmv_step<14>(w, nl, gid, lg, fReg, iReg, sF, goNC, goHM, stHC, stNC, th_s, trans_param); break;
        case 14: dmv_step<15>(w, nl, gid, lg, fReg, iReg, sF, goNC, goHM, stHC, stNC, th_s, trans_param); break;
        default: dmv_step<16>(w, nl, gid, lg, fReg, iReg, sF, goNC, goHM, stHC, stNC, th_s, trans_param); break;
        }
        __syncthreads();
    }

    // ---- final: out[b] = ln2 * lse_i( root[i] + FL[i][0] + FR[i][last] ), i<nl ----
    if (tid < 64) {
        const int last = nl - 1;
        float fl0 = (tid == 0)    ? stNC[0 * NMAX + 0]    : sF[tid * LDS_S + 0];
        float fre = (tid == last) ? stNC[1 * NMAX + last] : sF[tid * LDS_S + last];
        float xx  = (tid < nl) ? (root_s[tid] + fl0 + fre) : NEGV;
        float m = xx, s = 1.0f;
        #pragma unroll
        for (int off = 1; off < 64; off <<= 1)
            lse_merge(m, s, __shfl_xor(m, off, 64), __shfl_xor(s, off, 64));
        if (tid == 0) out[b] = (m + LOG2F(s)) * LN2;
    }
}

extern "C" void kernel_launch(void* const* d_in, const int* in_sizes, int n_in,
                              void* d_out, int out_size, void* d_ws, size_t ws_size,
                              hipStream_t stream) {
    // setup_inputs order: id_array, tag_array, len_array, root_param, trans_param, dec_param
    const int*   tag   = (const int*)d_in[1];
    const int*   len_a = (const int*)d_in[2];
    const float* root  = (const float*)d_in[3];
    const float* trans = (const float*)d_in[4];
    const float* dec   = (const float*)d_in[5];
    float* outp = (float*)d_out;
    const int B = in_sizes[2];   // 1024

    int* blk2item = (int*)d_ws;  // B ints

    int sortThreads = (B < 1024) ? ((B + 63) & ~63) : 1024;
    if (sortThreads < 64) sortThreads = 64;
    order_kernel<<<1, sortThreads, 0, stream>>>(len_a, blk2item, B);
    dmv_inside_kernel<<<B, BLOCK, 0, stream>>>(tag, len_a, root, trans, dec,
                                               blk2item, outp);
}

// Round 11
// 85.669 us; speedup vs baseline: 3.0007x; 3.0007x over previous
//
#include <hip/hip_runtime.h>

// DMV inside (log2-space), one block per batch item, 512 threads = 128 groups of 4.
//  - Baseline structure = R9 (70.3us, verified): sI/sF triangles in LDS,
//    per-step LOCAL x[]/y[] arrays only. NO persistent per-group register
//    caches (R10's fReg/iReg by-reference arrays -> scratch, 290MB traffic,
//    3.7x regression. R8's dual-inlined ISR bodies in one loop -> same. Do
//    not reintroduce either.)
//  - NEW vs R9: wave-uniform direction specialization. Fixed mapping:
//    gid<64 = right head h=gid (active iff h+w<nl); gid>=64 = left head
//    h=gid-64 (active iff w<=h<nl). Waves 0-3 are all-R, waves 4-7 all-L,
//    so each wave inlines ONE dmv_cell<NJ,ISR> body (constexpr DIR/SD):
//    per-j LDS offsets are compile-time immediates (left side rebased by
//    4*(NJ-1), only j<NJ-1 dereferenced, k<=w-2 guaranteed in-triangle).
//    Kills ~4NJ address v_adds/cell and lets SILoadStoreOptimizer fold
//    imm offsets + merge contiguous pairs into ds_read2_b32.
//    Rationale: R9 DS-pipe occupancy ~53us of 70us (one pipe/CU, 4 blocks)
//    is the binding resource; this cuts DS instrs ~1.6x.
//  - Diagonal (width-0) = stNC param selected at endpoints; CR/CL folded (ghm).
//  - Fused A+B, one barrier per width. template<NJ=ceil(w/4)> dispatch.
//  - Masked lanes' values pass through (k<w)?v:NEGV before any reduce.
//  - 4-lane DPP reduce (quad_perm xor1/xor2). 4 blocks/CU, 32 waves/CU.
//  - Load balance: counting-sort + quartile snake (R7: 127->83.6us).
//  - Spill sentinel: WRITE_SIZE must stay ~22KB (MB-scale => scratch, revert).

#define NEGV   -1000000000.0f
#define NMAX   64
#define LDS_S  69
#define BLOCK  512

#if __has_builtin(__builtin_amdgcn_exp2f)
#define EXP2F(x) __builtin_amdgcn_exp2f(x)
#else
#define EXP2F(x) __expf((x) * 0.6931471805599453f)
#endif
#if __has_builtin(__builtin_amdgcn_logf)
#define LOG2F(x) __builtin_amdgcn_logf(x)
#else
#define LOG2F(x) (__logf(x) * 1.4426950408889634f)
#endif
#define LOG2E 1.4426950408889634f
#define LN2   0.6931471805599453f

template<int CTRL>
__device__ __forceinline__ float dppf(float v) {
    return __int_as_float(__builtin_amdgcn_update_dpp(
        0, __float_as_int(v), CTRL, 0xF, 0xF, true));
}
__device__ __forceinline__ float grp4_max(float m) {
    m = fmaxf(m, dppf<0xB1>(m));    // quad_perm xor 1
    m = fmaxf(m, dppf<0x4E>(m));    // quad_perm xor 2
    return m;
}
__device__ __forceinline__ float grp4_sum(float s) {
    s += dppf<0xB1>(s);
    s += dppf<0x4E>(s);
    return s;
}

__device__ __forceinline__ void lse_merge(float& m, float& s, float mo, float so) {
    float mn = fmaxf(m, mo);
    s = s * EXP2F(m - mn) + so * EXP2F(mo - mn);
    m = mn;
}

// ---- pre-kernel: counting sort by length (descending) + quartile-snake map ----
__global__ void order_kernel(const int* __restrict__ len_arr,
                             int* __restrict__ blk2item, int B)
{
    __shared__ int hist[33];
    __shared__ int base[33];
    const int tid = threadIdx.x;
    if (tid < 33) hist[tid] = 0;
    __syncthreads();
    int bin = 0;
    if (tid < B) {
        bin = 64 - len_arr[tid];          // 0 = longest
        atomicAdd(&hist[bin], 1);
    }
    __syncthreads();
    if (tid == 0) {
        int acc = 0;
        for (int i = 0; i < 33; ++i) { base[i] = acc; acc += hist[i]; }
    }
    __syncthreads();
    if (tid < B) {
        int rank = atomicAdd(&base[bin], 1);   // sorted-descending rank
        int j;
        if ((B & 255) == 0) {                   // snake across quartile stripes
            int q = rank >> 8, pos = rank & 255;
            j = (q & 1) ? ((q << 8) + 255 - pos) : ((q << 8) + pos);
        } else {
            j = rank;
        }
        blk2item[j] = tid;
    }
}

// One fused A+B cell. NJ = ceil(w/4) and direction are compile-time.
// Called under a WAVE-UNIFORM branch (gid<64 vs >=64) so only one body
// inlines per wave — no dual-body register-pressure interaction (R8 lesson).
template<int NJ, bool ISR>
__device__ __forceinline__ void dmv_cell(
    const int w, const int h, const int lg,
    float* __restrict__ sI, float* __restrict__ sF,
    const float* __restrict__ goNC, const float* __restrict__ goHM,
    const float* __restrict__ stHC, const float* __restrict__ stNC,
    const int* __restrict__ th_s, const float* __restrict__ trans_param)
{
    constexpr int SD  = ISR ? 1 : 0;
    constexpr int DIR = ISR ? 1 : -1;
    constexpr int RB  = ISR ? 0 : 4 * (NJ - 1);   // rebase: all static offs >= 0
    const int e = ISR ? (h + w) : (h - w);
    const int lgo = ISR ? lg : -lg;               // signed lane offset

    // ---- phase A: I[h][e] = tr + lse_k( C[h][h+DIR*k]+go + F_other(k) ) ----
    const float tr  = trans_param[(th_s[h] * NMAX + th_s[e]) * 2 + SD] * LOG2E;
    const float gnc = goNC[SD * NMAX + h];
    const float ghm = goHM[SD * NMAX + h];
    const float dcO = stNC[(SD ^ 1) * NMAX + e];
    // static streams (j < NJ-1 only; k = lg+4j <= w-2 guaranteed in-triangle)
    const float* pF = sF + h * LDS_S + h + lgo - RB;          // own F row
    const float* pC = sF + e * LDS_S + (h + DIR) + lgo - RB;  // other F row
    float x[NJ];
    #pragma unroll
    for (int j = 0; j < NJ; ++j) {
        const int k = lg + 4 * j;
        if (j == NJ - 1) {                    // endpoint slot: runtime clamps
            const int kc = (k < w - 1) ? k : (w - 1);
            float vF = sF[h * LDS_S + h + DIR * kc];
            float vC = (k == w - 1) ? dcO : sF[e * LDS_S + h + DIR + DIR * kc];
            float base = (k == 0) ? gnc : (vF + ghm);
            float v = base + vC;
            x[j] = (k < w) ? v : NEGV;        // masks any garbage/NaN
        } else {
            const int o = ISR ? 4 * j : 4 * (NJ - 1 - j);   // compile-time
            float vF = pF[o];
            float vC = pC[o];
            float base = (j == 0 && k == 0) ? gnc : (vF + ghm);
            x[j] = base + vC;
        }
    }
    float mA = x[0];
    #pragma unroll
    for (int j = 1; j < NJ; ++j) mA = fmaxf(mA, x[j]);
    mA = grp4_max(mA);
    float sA = 0.f;
    #pragma unroll
    for (int j = 0; j < NJ; ++j) sA += EXP2F(x[j] - mA);
    sA = grp4_sum(sA);
    const float ir = mA + LOG2F(sA) + tr;     // group-uniform after DPP
    if (lg == 0) sI[h * LDS_S + e] = ir;

    // ---- phase B: F[h][e] = lse_k( I[h][h+DIR*(k+1)] + F[h+DIR*(k+1)][e] ) + st ----
    const float dcN = stNC[SD * NMAX + e];
    const float sth = stHC[SD * NMAX + h];
    const float* pI  = sI + h * LDS_S + (h + DIR) + lgo - RB;        // own I row
    const float* pF2 = sF + (h + DIR + lgo - RB) * LDS_S + e;        // F column e
    float y[NJ];
    #pragma unroll
    for (int j = 0; j < NJ; ++j) {
        const int k = lg + 4 * j;
        if (j == NJ - 1) {
            const int kc = (k < w - 1) ? k : (w - 1);
            float v1 = (k == w - 1) ? ir  : sI[h * LDS_S + h + DIR + DIR * kc];
            float v2 = (k == w - 1) ? dcN : sF[(h + DIR) * LDS_S + e + DIR * kc * LDS_S];
            float v  = v1 + v2;
            y[j] = (k < w) ? v : NEGV;
        } else {
            const int o = ISR ? 4 * j : 4 * (NJ - 1 - j);   // compile-time
            y[j] = pI[o] + pF2[o * LDS_S];
        }
    }
    float mB = y[0];
    #pragma unroll
    for (int j = 1; j < NJ; ++j) mB = fmaxf(mB, y[j]);
    mB = grp4_max(mB);
    float sB = 0.f;
    #pragma unroll
    for (int j = 0; j < NJ; ++j) sB += EXP2F(y[j] - mB);
    sB = grp4_sum(sB);
    if (lg == 0) sF[h * LDS_S + e] = mB + LOG2F(sB) + sth;
}

template<int NJ>
__device__ __forceinline__ void dmv_step(
    const int w, const int nl, const int gid, const int lg,
    float* __restrict__ sI, float* __restrict__ sF,
    const float* __restrict__ goNC, const float* __restrict__ goHM,
    const float* __restrict__ stHC, const float* __restrict__ stNC,
    const int* __restrict__ th_s, const float* __restrict__ trans_param)
{
    if (gid < 64) {                        // waves 0-3: right cells only
        const int h = gid;
        if (h + w < nl)
            dmv_cell<NJ, true>(w, h, lg, sI, sF, goNC, goHM, stHC, stNC,
                               th_s, trans_param);
    } else {                               // waves 4-7: left cells only
        const int h = gid - 64;
        if (w <= h && h < nl)
            dmv_cell<NJ, false>(w, h, lg, sI, sF, goNC, goHM, stHC, stNC,
                                th_s, trans_param);
    }
}

__global__ __launch_bounds__(BLOCK, 8)
void dmv_inside_kernel(const int* __restrict__ tag,
                       const int* __restrict__ len_arr,
                       const float* __restrict__ root_param,
                       const float* __restrict__ trans_param,
                       const float* __restrict__ dec_param,
                       const int* __restrict__ blk2item,
                       float* __restrict__ out)
{
    __shared__ float sI[NMAX * LDS_S];     // IR upper / IL lower triangle
    __shared__ float sF[NMAX * LDS_S];     // FR upper / FL lower triangle
    __shared__ float goNC[2 * NMAX];       // [0]=L, [1]=R (log2-scaled)
    __shared__ float goHM[2 * NMAX];       // go_hc - st_hc
    __shared__ float stHC[2 * NMAX];
    __shared__ float stNC[2 * NMAX];       // the "diagonal" of F
    __shared__ float root_s[NMAX];
    __shared__ int   th_s[NMAX];

    const int b   = blk2item[blockIdx.x];  // balanced assignment
    const int tid = threadIdx.x;
    const int nl  = len_arr[b];            // 32..64; output depends only on [0,nl)

    if (tid < NMAX) {
        int t = tag[b * NMAX + tid];
        th_s[tid] = t;
        const float* d = dec_param + t * 8;   // [dir][val][dec], L=0 R=1
        goNC[0 * NMAX + tid] = d[0] * LOG2E;
        stNC[0 * NMAX + tid] = d[1] * LOG2E;
        goHM[0 * NMAX + tid] = (d[2] - d[3]) * LOG2E;
        stHC[0 * NMAX + tid] = d[3] * LOG2E;
        goNC[1 * NMAX + tid] = d[4] * LOG2E;
        stNC[1 * NMAX + tid] = d[5] * LOG2E;
        goHM[1 * NMAX + tid] = (d[6] - d[7]) * LOG2E;
        stHC[1 * NMAX + tid] = d[7] * LOG2E;
        root_s[tid]          = root_param[t] * LOG2E;
    }
    __syncthreads();

    const int gid = tid >> 2;      // 0..63 right head h=gid; 64..127 left h=gid-64
    const int lg  = tid & 3;

    for (int w = 1; w < nl; ++w) {
        switch ((w - 1) >> 2) {    // block-uniform dispatch, NJ=ceil(w/4)
        case  0: dmv_step< 1>(w, nl, gid, lg, sI, sF, goNC, goHM, stHC, stNC, th_s, trans_param); break;
        case  1: dmv_step< 2>(w, nl, gid, lg, sI, sF, goNC, goHM, stHC, stNC, th_s, trans_param); break;
        case  2: dmv_step< 3>(w, nl, gid, lg, sI, sF, goNC, goHM, stHC, stNC, th_s, trans_param); break;
        case  3: dmv_step< 4>(w, nl, gid, lg, sI, sF, goNC, goHM, stHC, stNC, th_s, trans_param); break;
        case  4: dmv_step< 5>(w, nl, gid, lg, sI, sF, goNC, goHM, stHC, stNC, th_s, trans_param); break;
        case  5: dmv_step< 6>(w, nl, gid, lg, sI, sF, goNC, goHM, stHC, stNC, th_s, trans_param); break;
        case  6: dmv_step< 7>(w, nl, gid, lg, sI, sF, goNC, goHM, stHC, stNC, th_s, trans_param); break;
        case  7: dmv_step< 8>(w, nl, gid, lg, sI, sF, goNC, goHM, stHC, stNC, th_s, trans_param); break;
        case  8: dmv_step< 9>(w, nl, gid, lg, sI, sF, goNC, goHM, stHC, stNC, th_s, trans_param); break;
        case  9: dmv_step<10>(w, nl, gid, lg, sI, sF, goNC, goHM, stHC, stNC, th_s, trans_param); break;
        case 10: dmv_step<11>(w, nl, gid, lg, sI, sF, goNC, goHM, stHC, stNC, th_s, trans_param); break;
        case 11: dmv_step<12>(w, nl, gid, lg, sI, sF, goNC, goHM, stHC, stNC, th_s, trans_param); break;
        case 12: dmv_step<13>(w, nl, gid, lg, sI, sF, goNC, goHM, stHC, stNC, th_s, trans_param); break;
        case 13: dmv_step<14>(w, nl, gid, lg, sI, sF, goNC, goHM, stHC, stNC, th_s, trans_param); break;
        case 14: dmv_step<15>(w, nl, gid, lg, sI, sF, goNC, goHM, stHC, stNC, th_s, trans_param); break;
        default: dmv_step<16>(w, nl, gid, lg, sI, sF, goNC, goHM, stHC, stNC, th_s, trans_param); break;
        }
        __syncthreads();
    }

    // ---- final: out[b] = ln2 * lse_i( root[i] + FL[i][0] + FR[i][last] ), i<nl ----
    if (tid < 64) {
        const int last = nl - 1;
        float fl0 = (tid == 0)    ? stNC[0 * NMAX + 0]    : sF[tid * LDS_S + 0];
        float fre = (tid == last) ? stNC[1 * NMAX + last] : sF[tid * LDS_S + last];
        float xx  = (tid < nl) ? (root_s[tid] + fl0 + fre) : NEGV;
        float m = xx, s = 1.0f;
        #pragma unroll
        for (int off = 1; off < 64; off <<= 1)
            lse_merge(m, s, __shfl_xor(m, off, 64), __shfl_xor(s, off, 64));
        if (tid == 0) out[b] = (m + LOG2F(s)) * LN2;
    }
}

extern "C" void kernel_launch(void* const* d_in, const int* in_sizes, int n_in,
                              void* d_out, int out_size, void* d_ws, size_t ws_size,
                              hipStream_t stream) {
    // setup_inputs order: id_array, tag_array, len_array, root_param, trans_param, dec_param
    const int*   tag   = (const int*)d_in[1];
    const int*   len_a = (const int*)d_in[2];
    const float* root  = (const float*)d_in[3];
    const float* trans = (const float*)d_in[4];
    const float* dec   = (const float*)d_in[5];
    float* outp = (float*)d_out;
    const int B = in_sizes[2];   // 1024

    int* blk2item = (int*)d_ws;  // B ints

    int sortThreads = (B < 1024) ? ((B + 63) & ~63) : 1024;
    if (sortThreads < 64) sortThreads = 64;
    order_kernel<<<1, sortThreads, 0, stream>>>(len_a, blk2item, B);
    dmv_inside_kernel<<<B, BLOCK, 0, stream>>>(tag, len_a, root, trans, dec,
                                               blk2item, outp);
}

// Round 12
// 79.969 us; speedup vs baseline: 3.2146x; 1.0713x over previous
//
#include <hip/hip_runtime.h>
#include <hip/hip_fp16.h>

// DMV inside (log2-space), one block per batch item, 512 threads = 128 groups of 4.
// Structure = R9 (70.3us verified): compact cell mapping, runtime dir, local
// x[]/y[] only. (R8/R10/R11 direction-specialization all spilled — abandoned.)
// NEW: f16 charts + exact linear-trend removal.
//  - R9 is LDS-BANDWIDTH-bound: ~18MB DS traffic/CU at 128B/clk ~= 60us of
//    70us. b32->u16 halves bytes (vectorizing wouldn't — bytes, not instrs,
//    are the limit).
//  - Charts stored as __half with F' = F + ALPHA*width, I' = I + ALPHA*width
//    (ALPHA=8 ~ the -8/width log2 drift). Algebra telescopes EXACTLY:
//      phase A: all x(k) shift by ALPHA*(w-1) -> ir' = lse + tr + ALPHA
//               (folded into tr load).
//      phase B: shifts cancel -> code unchanged.
//      final:   fl0'+fre' shift uniformly by ALPHA*(nl-1) -> one subtract.
//    Residual |F'| ~ O(10) -> f16 ulp ~0.01 -> accum err << 5.72 threshold.
//  - Masked/garbage reads (incl. possible NaN from uninit f16 LDS) pass
//    through (k<w)?v:NEGV cndmask before any reduce — NaN never propagates.
//  - Fused A+B, one barrier per width; template<NJ=ceil(w/4)> dispatch;
//    4-lane DPP reduce; 4 blocks/CU (wave-capped), snake load balance (R7).
//  - Spill sentinel: WRITE_SIZE must stay ~22KB (MB-scale => scratch, revert).

#define NEGV   -1000000000.0f
#define NMAX   64
#define LDS_S  69
#define BLOCK  512
#define ALPHA  8.0f

#if __has_builtin(__builtin_amdgcn_exp2f)
#define EXP2F(x) __builtin_amdgcn_exp2f(x)
#else
#define EXP2F(x) __expf((x) * 0.6931471805599453f)
#endif
#if __has_builtin(__builtin_amdgcn_logf)
#define LOG2F(x) __builtin_amdgcn_logf(x)
#else
#define LOG2F(x) (__logf(x) * 1.4426950408889634f)
#endif
#define LOG2E 1.4426950408889634f
#define LN2   0.6931471805599453f

template<int CTRL>
__device__ __forceinline__ float dppf(float v) {
    return __int_as_float(__builtin_amdgcn_update_dpp(
        0, __float_as_int(v), CTRL, 0xF, 0xF, true));
}
__device__ __forceinline__ float grp4_max(float m) {
    m = fmaxf(m, dppf<0xB1>(m));    // quad_perm xor 1
    m = fmaxf(m, dppf<0x4E>(m));    // quad_perm xor 2
    return m;
}
__device__ __forceinline__ float grp4_sum(float s) {
    s += dppf<0xB1>(s);
    s += dppf<0x4E>(s);
    return s;
}

__device__ __forceinline__ void lse_merge(float& m, float& s, float mo, float so) {
    float mn = fmaxf(m, mo);
    s = s * EXP2F(m - mn) + so * EXP2F(mo - mn);
    m = mn;
}

__device__ __forceinline__ float h2f(const __half h) { return __half2float(h); }

// ---- pre-kernel: counting sort by length (descending) + quartile-snake map ----
__global__ void order_kernel(const int* __restrict__ len_arr,
                             int* __restrict__ blk2item, int B)
{
    __shared__ int hist[33];
    __shared__ int base[33];
    const int tid = threadIdx.x;
    if (tid < 33) hist[tid] = 0;
    __syncthreads();
    int bin = 0;
    if (tid < B) {
        bin = 64 - len_arr[tid];          // 0 = longest
        atomicAdd(&hist[bin], 1);
    }
    __syncthreads();
    if (tid == 0) {
        int acc = 0;
        for (int i = 0; i < 33; ++i) { base[i] = acc; acc += hist[i]; }
    }
    __syncthreads();
    if (tid < B) {
        int rank = atomicAdd(&base[bin], 1);   // sorted-descending rank
        int j;
        if ((B & 255) == 0) {                   // snake across quartile stripes
            int q = rank >> 8, pos = rank & 255;
            j = (q & 1) ? ((q << 8) + 255 - pos) : ((q << 8) + pos);
        } else {
            j = rank;
        }
        blk2item[j] = tid;
    }
}

// Fused A+B step for this group's cell. NJ = ceil(w/4) known at compile time.
template<int NJ>
__device__ __forceinline__ void dmv_step(
    const int w, const int cd, const int gid, const int lg,
    __half* __restrict__ sI, __half* __restrict__ sF,
    const float* __restrict__ goNC, const float* __restrict__ goHM,
    const float* __restrict__ stHC, const float* __restrict__ stNC,
    const int* __restrict__ th_s, const float* __restrict__ trans_param)
{
    const int cells = 2 * cd;
    if (gid >= cells) return;             // 128 groups >= 126 cells: single trip
    const bool isR = gid < cd;
    const int  sd  = isR ? 1 : 0;
    const int  dir = isR ? 1 : -1;
    const int  h   = isR ? gid : (w + gid - cd);
    const int  e   = h + dir * w;

    // ---- phase A: I'[h][e] = tr + ALPHA + lse_k( stored sums ) ----
    const float tr  = trans_param[(th_s[h] * NMAX + th_s[e]) * 2 + sd] * LOG2E
                      + ALPHA;            // +ALPHA: I' = I + ALPHA*w (exact fold)
    const float gnc = goNC[sd * NMAX + h];
    const float ghm = goHM[sd * NMAX + h];
    const float dcO = stNC[(sd ^ 1) * NMAX + e];
    const int   oF  = h * LDS_S + h;        // own F' row,   elem [dir*k]
    const int   oC  = e * LDS_S + h + dir;  // other F' row, elem [dir*k]
    float x[NJ];
    #pragma unroll
    for (int j = 0; j < NJ; ++j) {
        const int k = lg + 4 * j;
        if (j == NJ - 1) {                   // static: endpoint handling here only
            const int  kc = (k < w - 1) ? k : (w - 1);
            float vF = h2f(sF[oF + dir * kc]);
            float vC = (k == w - 1) ? dcO : h2f(sF[oC + dir * kc]);
            float base = (k == 0) ? gnc : (vF + ghm);
            float v = base + vC;
            x[j] = (k < w) ? v : NEGV;       // masks any garbage/NaN
        } else {                             // k < w-1 guaranteed in-triangle
            float vF = h2f(sF[oF + dir * k]);
            float vC = h2f(sF[oC + dir * k]);
            float base = (j == 0 && k == 0) ? gnc : (vF + ghm);
            x[j] = base + vC;
        }
    }
    float mA = x[0];
    #pragma unroll
    for (int j = 1; j < NJ; ++j) mA = fmaxf(mA, x[j]);
    mA = grp4_max(mA);
    float sA = 0.f;
    #pragma unroll
    for (int j = 0; j < NJ; ++j) sA += EXP2F(x[j] - mA);
    sA = grp4_sum(sA);
    const float ir = mA + LOG2F(sA) + tr;    // group-uniform after DPP (= I')
    if (lg == 0) sI[h * LDS_S + e] = __float2half(ir);

    // ---- phase B: shifts cancel exactly -> identical code to f32 version ----
    const float dcN = stNC[sd * NMAX + e];
    const float sth = stHC[sd * NMAX + h];
    const int   oI  = h * LDS_S + h + dir;    // elem [dir*k]
    const int   oF2 = (h + dir) * LDS_S + e;  // elem [dir*k*LDS_S]
    float y[NJ];
    #pragma unroll
    for (int j = 0; j < NJ; ++j) {
        const int k = lg + 4 * j;
        if (j == NJ - 1) {
            const int  kc = (k < w - 1) ? k : (w - 1);
            float v1 = (k == w - 1) ? ir  : h2f(sI[oI + dir * kc]);
            float v2 = (k == w - 1) ? dcN : h2f(sF[oF2 + dir * kc * LDS_S]);
            float v  = v1 + v2;
            y[j] = (k < w) ? v : NEGV;
        } else {
            y[j] = h2f(sI[oI + dir * k]) + h2f(sF[oF2 + dir * k * LDS_S]);
        }
    }
    float mB = y[0];
    #pragma unroll
    for (int j = 1; j < NJ; ++j) mB = fmaxf(mB, y[j]);
    mB = grp4_max(mB);
    float sB = 0.f;
    #pragma unroll
    for (int j = 0; j < NJ; ++j) sB += EXP2F(y[j] - mB);
    sB = grp4_sum(sB);
    if (lg == 0) sF[h * LDS_S + e] = __float2half(mB + LOG2F(sB) + sth);
}

__global__ __launch_bounds__(BLOCK, 8)
void dmv_inside_kernel(const int* __restrict__ tag,
                       const int* __restrict__ len_arr,
                       const float* __restrict__ root_param,
                       const float* __restrict__ trans_param,
                       const float* __restrict__ dec_param,
                       const int* __restrict__ blk2item,
                       float* __restrict__ out)
{
    __shared__ __half sI[NMAX * LDS_S];    // I' (trend-removed) triangle, f16
    __shared__ __half sF[NMAX * LDS_S];    // F' triangle, f16
    __shared__ float goNC[2 * NMAX];       // [0]=L, [1]=R (log2-scaled)
    __shared__ float goHM[2 * NMAX];       // go_hc - st_hc
    __shared__ float stHC[2 * NMAX];
    __shared__ float stNC[2 * NMAX];       // width-0 "diagonal" of F (shift 0)
    __shared__ float root_s[NMAX];
    __shared__ int   th_s[NMAX];

    const int b   = blk2item[blockIdx.x];  // balanced assignment
    const int tid = threadIdx.x;
    const int nl  = len_arr[b];            // 32..64; output depends only on [0,nl)

    if (tid < NMAX) {
        int t = tag[b * NMAX + tid];
        th_s[tid] = t;
        const float* d = dec_param + t * 8;   // [dir][val][dec], L=0 R=1
        goNC[0 * NMAX + tid] = d[0] * LOG2E;
        stNC[0 * NMAX + tid] = d[1] * LOG2E;
        goHM[0 * NMAX + tid] = (d[2] - d[3]) * LOG2E;
        stHC[0 * NMAX + tid] = d[3] * LOG2E;
        goNC[1 * NMAX + tid] = d[4] * LOG2E;
        stNC[1 * NMAX + tid] = d[5] * LOG2E;
        goHM[1 * NMAX + tid] = (d[6] - d[7]) * LOG2E;
        stHC[1 * NMAX + tid] = d[7] * LOG2E;
        root_s[tid]          = root_param[t] * LOG2E;
    }
    __syncthreads();

    const int gid = tid >> 2;      // 0..127 — one DP cell per 4-lane group
    const int lg  = tid & 3;

    for (int w = 1; w < nl; ++w) {
        const int cd = nl - w;
        switch ((w - 1) >> 2) {    // block-uniform scalar dispatch, NJ=ceil(w/4)
        case  0: dmv_step< 1>(w, cd, gid, lg, sI, sF, goNC, goHM, stHC, stNC, th_s, trans_param); break;
        case  1: dmv_step< 2>(w, cd, gid, lg, sI, sF, goNC, goHM, stHC, stNC, th_s, trans_param); break;
        case  2: dmv_step< 3>(w, cd, gid, lg, sI, sF, goNC, goHM, stHC, stNC, th_s, trans_param); break;
        case  3: dmv_step< 4>(w, cd, gid, lg, sI, sF, goNC, goHM, stHC, stNC, th_s, trans_param); break;
        case  4: dmv_step< 5>(w, cd, gid, lg, sI, sF, goNC, goHM, stHC, stNC, th_s, trans_param); break;
        case  5: dmv_step< 6>(w, cd, gid, lg, sI, sF, goNC, goHM, stHC, stNC, th_s, trans_param); break;
        case  6: dmv_step< 7>(w, cd, gid, lg, sI, sF, goNC, goHM, stHC, stNC, th_s, trans_param); break;
        case  7: dmv_step< 8>(w, cd, gid, lg, sI, sF, goNC, goHM, stHC, stNC, th_s, trans_param); break;
        case  8: dmv_step< 9>(w, cd, gid, lg, sI, sF, goNC, goHM, stHC, stNC, th_s, trans_param); break;
        case  9: dmv_step<10>(w, cd, gid, lg, sI, sF, goNC, goHM, stHC, stNC, th_s, trans_param); break;
        case 10: dmv_step<11>(w, cd, gid, lg, sI, sF, goNC, goHM, stHC, stNC, th_s, trans_param); break;
        case 11: dmv_step<12>(w, cd, gid, lg, sI, sF, goNC, goHM, stHC, stNC, th_s, trans_param); break;
        case 12: dmv_step<13>(w, cd, gid, lg, sI, sF, goNC, goHM, stHC, stNC, th_s, trans_param); break;
        case 13: dmv_step<14>(w, cd, gid, lg, sI, sF, goNC, goHM, stHC, stNC, th_s, trans_param); break;
        case 14: dmv_step<15>(w, cd, gid, lg, sI, sF, goNC, goHM, stHC, stNC, th_s, trans_param); break;
        default: dmv_step<16>(w, cd, gid, lg, sI, sF, goNC, goHM, stHC, stNC, th_s, trans_param); break;
        }
        __syncthreads();
    }

    // ---- final: stored fl0'+fre' shift uniformly by ALPHA*(nl-1) ----
    // out[b] = ln2 * ( lse_i( root[i] + FL'[i][0] + FR'[i][last] ) - ALPHA*last )
    if (tid < 64) {
        const int last = nl - 1;
        float fl0 = (tid == 0)    ? stNC[0 * NMAX + 0]
                                  : h2f(sF[tid * LDS_S + 0]);
        float fre = (tid == last) ? stNC[1 * NMAX + last]
                                  : h2f(sF[tid * LDS_S + last]);
        float xx  = (tid < nl) ? (root_s[tid] + fl0 + fre) : NEGV;
        float m = xx, s = 1.0f;
        #pragma unroll
        for (int off = 1; off < 64; off <<= 1)
            lse_merge(m, s, __shfl_xor(m, off, 64), __shfl_xor(s, off, 64));
        if (tid == 0) out[b] = (m + LOG2F(s) - ALPHA * last) * LN2;
    }
}

extern "C" void kernel_launch(void* const* d_in, const int* in_sizes, int n_in,
                              void* d_out, int out_size, void* d_ws, size_t ws_size,
                              hipStream_t stream) {
    // setup_inputs order: id_array, tag_array, len_array, root_param, trans_param, dec_param
    const int*   tag   = (const int*)d_in[1];
    const int*   len_a = (const int*)d_in[2];
    const float* root  = (const float*)d_in[3];
    const float* trans = (const float*)d_in[4];
    const float* dec   = (const float*)d_in[5];
    float* outp = (float*)d_out;
    const int B = in_sizes[2];   // 1024

    int* blk2item = (int*)d_ws;  // B ints

    int sortThreads = (B < 1024) ? ((B + 63) & ~63) : 1024;
    if (sortThreads < 64) sortThreads = 64;
    order_kernel<<<1, sortThreads, 0, stream>>>(len_a, blk2item, B);
    dmv_inside_kernel<<<B, BLOCK, 0, stream>>>(tag, len_a, root, trans, dec,
                                               blk2item, outp);
}

// Round 13
// 76.796 us; speedup vs baseline: 3.3474x; 1.0413x over previous
//
#include <hip/hip_runtime.h>

// DMV inside (log2-space), one block per batch item, 512 threads = 64 groups of 8.
// PAIRED-SPAN formulation: group g (< cd = nl-w) owns span (h=g, e=h+w) and
// computes BOTH its right cell (head h) and left cell (head e).
//  - Phase A of the two cells reads the SAME segments FR[h][h..e-1] and
//    FL[e][h+1..e]: load once (vF,vC), form both x_R and x_L (lse is
//    commutative, order within the k-domain is irrelevant).
//  - Absolute-span enumeration removes runtime `dir`: ALL six streams walk
//    forward (+k or +k*LDS_S) from a per-cell base -> compile-time per-j
//    immediates, single template body (no R8/R10/R11 dual-body spill risk),
//    ds_read2-mergeable. DS instrs/pair-step: 8*ceil(w/4)+4 -> 6*ceil(w/8)+2.
//    (R12 lesson: DS pipe is ISSUE-limited, not byte-limited — f16 didn't help;
//    fewer instructions is the lever. f32 charts restored.)
//  - IR upper/IL lower share sI; FR upper/FL lower share sF; diagonals
//    (width-0) = stNC params selected at k==0 / k==w-1 endpoints; CR/CL
//    folded via ghm = go_hc - st_hc.
//  - Fused A+B, one barrier per width; B needs width-w I only from its own
//    pair (irR/irL registers). template<NJ=ceil(w/8)> block-uniform dispatch.
//  - Garbage/stale LDS reads (diag slots, width-w slot, tail lanes) are all
//    value-replaced or NEGV-masked BEFORE any reduce; addresses stay in-bounds.
//  - 8-lane DPP reduce (quad_perm xor1/xor2 + row_half_mirror, proven R5-R7).
//  - 4 blocks/CU (LDS 37.9K), 32 waves/CU; snake load balance (R7).
//  - Spill sentinel: WRITE_SIZE must stay ~22KB (MB-scale => scratch, revert).

#define NEGV   -1000000000.0f
#define NMAX   64
#define LDS_S  69
#define BLOCK  512

#if __has_builtin(__builtin_amdgcn_exp2f)
#define EXP2F(x) __builtin_amdgcn_exp2f(x)
#else
#define EXP2F(x) __expf((x) * 0.6931471805599453f)
#endif
#if __has_builtin(__builtin_amdgcn_logf)
#define LOG2F(x) __builtin_amdgcn_logf(x)
#else
#define LOG2F(x) (__logf(x) * 1.4426950408889634f)
#endif
#define LOG2E 1.4426950408889634f
#define LN2   0.6931471805599453f

template<int CTRL>
__device__ __forceinline__ float dppf(float v) {
    return __int_as_float(__builtin_amdgcn_update_dpp(
        0, __float_as_int(v), CTRL, 0xF, 0xF, true));
}
__device__ __forceinline__ float grp8_max(float m) {
    m = fmaxf(m, dppf<0xB1>(m));    // quad_perm xor 1
    m = fmaxf(m, dppf<0x4E>(m));    // quad_perm xor 2
    m = fmaxf(m, dppf<0x141>(m));   // row_half_mirror (joins quads in 8-lane group)
    return m;
}
__device__ __forceinline__ float grp8_sum(float s) {
    s += dppf<0xB1>(s);
    s += dppf<0x4E>(s);
    s += dppf<0x141>(s);
    return s;
}

__device__ __forceinline__ void lse_merge(float& m, float& s, float mo, float so) {
    float mn = fmaxf(m, mo);
    s = s * EXP2F(m - mn) + so * EXP2F(mo - mn);
    m = mn;
}

// ---- pre-kernel: counting sort by length (descending) + quartile-snake map ----
__global__ void order_kernel(const int* __restrict__ len_arr,
                             int* __restrict__ blk2item, int B)
{
    __shared__ int hist[33];
    __shared__ int base[33];
    const int tid = threadIdx.x;
    if (tid < 33) hist[tid] = 0;
    __syncthreads();
    int bin = 0;
    if (tid < B) {
        bin = 64 - len_arr[tid];          // 0 = longest
        atomicAdd(&hist[bin], 1);
    }
    __syncthreads();
    if (tid == 0) {
        int acc = 0;
        for (int i = 0; i < 33; ++i) { base[i] = acc; acc += hist[i]; }
    }
    __syncthreads();
    if (tid < B) {
        int rank = atomicAdd(&base[bin], 1);   // sorted-descending rank
        int j;
        if ((B & 255) == 0) {                   // snake across quartile stripes
            int q = rank >> 8, pos = rank & 255;
            j = (q & 1) ? ((q << 8) + 255 - pos) : ((q << 8) + pos);
        } else {
            j = rank;
        }
        blk2item[j] = tid;
    }
}

// Paired fused A+B step for span (h=gid, e=h+w). NJ = ceil(w/8), compile-time.
template<int NJ>
__device__ __forceinline__ void dmv_step(
    const int w, const int cd, const int gid, const int lg,
    float* __restrict__ sI, float* __restrict__ sF,
    const float* __restrict__ goNC, const float* __restrict__ goHM,
    const float* __restrict__ stHC, const float* __restrict__ stNC,
    const int* __restrict__ th_s, const float* __restrict__ trans_param)
{
    if (gid >= cd) return;
    const int h = gid, e = h + w;

    const int thh = th_s[h], the = th_s[e];
    const float trR  = trans_param[(thh * NMAX + the) * 2 + 1] * LOG2E;
    const float trL  = trans_param[(the * NMAX + thh) * 2 + 0] * LOG2E;
    const float gncR = goNC[NMAX + h], ghmR = goHM[NMAX + h];
    const float gncL = goNC[e],        ghmL = goHM[e];
    const float dcR  = stNC[NMAX + h];   // FR[h][h] (width-0 diag)
    const float dcL  = stNC[e];          // FL[e][e]
    const float dcRe = stNC[NMAX + e];   // FR[e][e]
    const float dcLh = stNC[h];          // FL[h][h]

    // ---- phase A (shared loads): vF = FR[h][h+k], vC = FL[e][h+1+k] ----
    // x_R(k) = (k==0 ? gncR : vF+ghmR) + (k==w-1 ? dcL : vC)
    // x_L(k) = (k==w-1 ? gncL : vC+ghmL) + (k==0 ? dcR : vF)
    const int aF = h * LDS_S + h;        // +k
    const int aC = e * LDS_S + h + 1;    // +k
    float xR[NJ], xL[NJ];
    #pragma unroll
    for (int j = 0; j < NJ; ++j) {
        const int k = lg + 8 * j;
        if (j == NJ - 1) {                       // endpoint slot (and NJ==1 case)
            const int kc = (k < w) ? k : (w - 1);
            float vF = sF[aF + kc];
            float vC = sF[aC + kc];
            float xr = ((k == 0) ? gncR : vF + ghmR) + ((k == w - 1) ? dcL : vC);
            float xl = ((k == w - 1) ? gncL : vC + ghmL) + ((k == 0) ? dcR : vF);
            xR[j] = (k < w) ? xr : NEGV;
            xL[j] = (k < w) ? xl : NEGV;
        } else if (j == 0) {                     // NJ>=2 -> w>=9 -> k<=7<=w-2
            float vF = sF[aF + k];
            float vC = sF[aC + k];
            xR[j] = ((k == 0) ? gncR : vF + ghmR) + vC;
            xL[j] = (vC + ghmL) + ((k == 0) ? dcR : vF);
        } else {                                 // 8 <= k <= w-2: pure interior
            float vF = sF[aF + k];
            float vC = sF[aC + k];
            float t = vF + vC;
            xR[j] = t + ghmR;
            xL[j] = t + ghmL;
        }
    }
    float mR = xR[0], mL = xL[0];
    #pragma unroll
    for (int j = 1; j < NJ; ++j) { mR = fmaxf(mR, xR[j]); mL = fmaxf(mL, xL[j]); }
    mR = grp8_max(mR); mL = grp8_max(mL);
    float sR = 0.f, sLs = 0.f;
    #pragma unroll
    for (int j = 0; j < NJ; ++j) { sR += EXP2F(xR[j] - mR); sLs += EXP2F(xL[j] - mL); }
    sR = grp8_sum(sR); sLs = grp8_sum(sLs);
    const float irR = mR + LOG2F(sR) + trR;     // group-uniform after DPP
    const float irL = mL + LOG2F(sLs) + trL;
    if (lg < 2) sI[lg ? (e * LDS_S + h) : (h * LDS_S + e)] = lg ? irL : irR;

    // ---- phase B: y_R(k) = IR[h][h+1+k] + FR[h+1+k][e]  (k==w-1: irR + dcRe)
    //              y_L(k) = IL[e][h+k]   + FL[h+k][h]     (k==0  : irL + dcLh)
    const int bI1 = h * LDS_S + h + 1;       // +k
    const int bF1 = (h + 1) * LDS_S + e;     // +k*LDS_S
    const int bI2 = e * LDS_S + h;           // +k
    const int bF2 = h * LDS_S + h;           // +k*LDS_S
    float yR[NJ], yL[NJ];
    #pragma unroll
    for (int j = 0; j < NJ; ++j) {
        const int k = lg + 8 * j;
        if (j == NJ - 1) {
            const int kc = (k < w) ? k : (w - 1);
            float i1 = sI[bI1 + kc];
            float f1 = sF[bF1 + kc * LDS_S];
            float i2 = sI[bI2 + kc];
            float f2 = sF[bF2 + kc * LDS_S];
            float yr = ((k == w - 1) ? irR : i1) + ((k == w - 1) ? dcRe : f1);
            float yl = ((k == 0) ? irL : i2) + ((k == 0) ? dcLh : f2);
            yR[j] = (k < w) ? yr : NEGV;
            yL[j] = (k < w) ? yl : NEGV;
        } else if (j == 0) {                     // k <= w-2; k==0 possible
            float i1 = sI[bI1 + k];
            float f1 = sF[bF1 + k * LDS_S];
            float i2 = sI[bI2 + k];
            float f2 = sF[bF2 + k * LDS_S];
            yR[j] = i1 + f1;
            yL[j] = ((k == 0) ? irL : i2) + ((k == 0) ? dcLh : f2);
        } else {
            yR[j] = sI[bI1 + k] + sF[bF1 + k * LDS_S];
            yL[j] = sI[bI2 + k] + sF[bF2 + k * LDS_S];
        }
    }
    float mBR = yR[0], mBL = yL[0];
    #pragma unroll
    for (int j = 1; j < NJ; ++j) { mBR = fmaxf(mBR, yR[j]); mBL = fmaxf(mBL, yL[j]); }
    mBR = grp8_max(mBR); mBL = grp8_max(mBL);
    float sBR = 0.f, sBL = 0.f;
    #pragma unroll
    for (int j = 0; j < NJ; ++j) { sBR += EXP2F(yR[j] - mBR); sBL += EXP2F(yL[j] - mBL); }
    sBR = grp8_sum(sBR); sBL = grp8_sum(sBL);
    const float fR = mBR + LOG2F(sBR) + stHC[NMAX + h];
    const float fL = mBL + LOG2F(sBL) + stHC[e];
    if (lg < 2) sF[lg ? (e * LDS_S + h) : (h * LDS_S + e)] = lg ? fL : fR;
}

__global__ __launch_bounds__(BLOCK, 8)
void dmv_inside_kernel(const int* __restrict__ tag,
                       const int* __restrict__ len_arr,
                       const float* __restrict__ root_param,
                       const float* __restrict__ trans_param,
                       const float* __restrict__ dec_param,
                       const int* __restrict__ blk2item,
                       float* __restrict__ out)
{
    __shared__ float sI[NMAX * LDS_S];     // IR upper / IL lower triangle
    __shared__ float sF[NMAX * LDS_S];     // FR upper / FL lower triangle
    __shared__ float goNC[2 * NMAX];       // [0]=L, [1]=R (log2-scaled)
    __shared__ float goHM[2 * NMAX];       // go_hc - st_hc
    __shared__ float stHC[2 * NMAX];
    __shared__ float stNC[2 * NMAX];       // width-0 "diagonal" of F
    __shared__ float root_s[NMAX];
    __shared__ int   th_s[NMAX];

    const int b   = blk2item[blockIdx.x];  // balanced assignment
    const int tid = threadIdx.x;
    const int nl  = len_arr[b];            // 32..64; output depends only on [0,nl)

    if (tid < NMAX) {
        int t = tag[b * NMAX + tid];
        th_s[tid] = t;
        const float* d = dec_param + t * 8;   // [dir][val][dec], L=0 R=1
        goNC[0 * NMAX + tid] = d[0] * LOG2E;
        stNC[0 * NMAX + tid] = d[1] * LOG2E;
        goHM[0 * NMAX + tid] = (d[2] - d[3]) * LOG2E;
        stHC[0 * NMAX + tid] = d[3] * LOG2E;
        goNC[1 * NMAX + tid] = d[4] * LOG2E;
        stNC[1 * NMAX + tid] = d[5] * LOG2E;
        goHM[1 * NMAX + tid] = (d[6] - d[7]) * LOG2E;
        stHC[1 * NMAX + tid] = d[7] * LOG2E;
        root_s[tid]          = root_param[t] * LOG2E;
    }
    __syncthreads();

    const int gid = tid >> 3;      // 0..63 — one span-PAIR per 8-lane group
    const int lg  = tid & 7;

    for (int w = 1; w < nl; ++w) {
        const int cd = nl - w;     // pairs this step (<= 63 <= 64 groups)
        switch ((w - 1) >> 3) {    // block-uniform dispatch, NJ=ceil(w/8)
        case 0: dmv_step<1>(w, cd, gid, lg, sI, sF, goNC, goHM, stHC, stNC, th_s, trans_param); break;
        case 1: dmv_step<2>(w, cd, gid, lg, sI, sF, goNC, goHM, stHC, stNC, th_s, trans_param); break;
        case 2: dmv_step<3>(w, cd, gid, lg, sI, sF, goNC, goHM, stHC, stNC, th_s, trans_param); break;
        case 3: dmv_step<4>(w, cd, gid, lg, sI, sF, goNC, goHM, stHC, stNC, th_s, trans_param); break;
        case 4: dmv_step<5>(w, cd, gid, lg, sI, sF, goNC, goHM, stHC, stNC, th_s, trans_param); break;
        case 5: dmv_step<6>(w, cd, gid, lg, sI, sF, goNC, goHM, stHC, stNC, th_s, trans_param); break;
        case 6: dmv_step<7>(w, cd, gid, lg, sI, sF, goNC, goHM, stHC, stNC, th_s, trans_param); break;
        default: dmv_step<8>(w, cd, gid, lg, sI, sF, goNC, goHM, stHC, stNC, th_s, trans_param); break;
        }
        __syncthreads();
    }

    // ---- final: out[b] = ln2 * lse_i( root[i] + FL[i][0] + FR[i][last] ), i<nl ----
    if (tid < 64) {
        const int last = nl - 1;
        float fl0 = (tid == 0)    ? stNC[0 * NMAX + 0]    : sF[tid * LDS_S + 0];
        float fre = (tid == last) ? stNC[1 * NMAX + last] : sF[tid * LDS_S + last];
        float xx  = (tid < nl) ? (root_s[tid] + fl0 + fre) : NEGV;
        float m = xx, s = 1.0f;
        #pragma unroll
        for (int off = 1; off < 64; off <<= 1)
            lse_merge(m, s, __shfl_xor(m, off, 64), __shfl_xor(s, off, 64));
        if (tid == 0) out[b] = (m + LOG2F(s)) * LN2;
    }
}

extern "C" void kernel_launch(void* const* d_in, const int* in_sizes, int n_in,
                              void* d_out, int out_size, void* d_ws, size_t ws_size,
                              hipStream_t stream) {
    // setup_inputs order: id_array, tag_array, len_array, root_param, trans_param, dec_param
    const int*   tag   = (const int*)d_in[1];
    const int*   len_a = (const int*)d_in[2];
    const float* root  = (const float*)d_in[3];
    const float* trans = (const float*)d_in[4];
    const float* dec   = (const float*)d_in[5];
    float* outp = (float*)d_out;
    const int B = in_sizes[2];   // 1024

    int* blk2item = (int*)d_ws;  // B ints

    int sortThreads = (B < 1024) ? ((B + 63) & ~63) : 1024;
    if (sortThreads < 64) sortThreads = 64;
    order_kernel<<<1, sortThreads, 0, stream>>>(len_a, blk2item, B);
    dmv_inside_kernel<<<B, BLOCK, 0, stream>>>(tag, len_a, root, trans, dec,
                                               blk2item, outp);
}

// Round 14
// 66.619 us; speedup vs baseline: 3.8588x; 1.1528x over previous
//
#include <hip/hip_runtime.h>

// DMV inside (log2-space), one block per batch item, 512 threads = 128 groups of 4.
// Geometry/structure = R9 (70.3us best): compact cell mapping, single template
// body, local x[]/y[] only, 4-lane DPP reduce, fused A+B, 1 barrier/width.
// NEW: ASCENDING-K REMAP for left cells (k' = w-1-k; LSE is commutative), so
// ALL four streams walk forward (+k or +k*LDS_S) from runtime per-cell bases
// with compile-time per-j offsets:
//   right: ownF=h*S+h,     othF=e*S+h+1, I=h*S+h+1, Fcol=(h+1)*S+e
//   left:  ownF=h*S+h-w+1, othF=e*S+e,   I=h*S+e,   Fcol= e*S+e
// Endpoint specials swap ends for left cells; unified as slot-selects
//   kG = isR?0:w-1 (gnc), kD = isR?w-1:0 (dcO), kS = isR?w-1:0 (ir,dcN)
// evaluated ONLY in the two boundary j-slots; interior slots are pure adds.
// This removes the per-j dir*k address VALU (the surviving slice of the 47us
// VALU floor measured constant across R9/R12/R13) WITHOUT direction-templated
// dual bodies (R8/R10/R11 spill trap) — it's an index remap, not codegen split.
// R12 lesson: not byte-bound (f16 lost). R13 lesson: not DS-issue-bound
// (2.7x fewer DS instrs lost); VALU issue is the binding resource.
// Spill sentinel: WRITE_SIZE must stay ~22KB (MB-scale => scratch, revert to R9).

#define NEGV   -1000000000.0f
#define NMAX   64
#define LDS_S  69
#define BLOCK  512

#if __has_builtin(__builtin_amdgcn_exp2f)
#define EXP2F(x) __builtin_amdgcn_exp2f(x)
#else
#define EXP2F(x) __expf((x) * 0.6931471805599453f)
#endif
#if __has_builtin(__builtin_amdgcn_logf)
#define LOG2F(x) __builtin_amdgcn_logf(x)
#else
#define LOG2F(x) (__logf(x) * 1.4426950408889634f)
#endif
#define LOG2E 1.4426950408889634f
#define LN2   0.6931471805599453f

template<int CTRL>
__device__ __forceinline__ float dppf(float v) {
    return __int_as_float(__builtin_amdgcn_update_dpp(
        0, __float_as_int(v), CTRL, 0xF, 0xF, true));
}
__device__ __forceinline__ float grp4_max(float m) {
    m = fmaxf(m, dppf<0xB1>(m));    // quad_perm xor 1
    m = fmaxf(m, dppf<0x4E>(m));    // quad_perm xor 2
    return m;
}
__device__ __forceinline__ float grp4_sum(float s) {
    s += dppf<0xB1>(s);
    s += dppf<0x4E>(s);
    return s;
}

__device__ __forceinline__ void lse_merge(float& m, float& s, float mo, float so) {
    float mn = fmaxf(m, mo);
    s = s * EXP2F(m - mn) + so * EXP2F(mo - mn);
    m = mn;
}

// ---- pre-kernel: counting sort by length (descending) + quartile-snake map ----
__global__ void order_kernel(const int* __restrict__ len_arr,
                             int* __restrict__ blk2item, int B)
{
    __shared__ int hist[33];
    __shared__ int base[33];
    const int tid = threadIdx.x;
    if (tid < 33) hist[tid] = 0;
    __syncthreads();
    int bin = 0;
    if (tid < B) {
        bin = 64 - len_arr[tid];          // 0 = longest
        atomicAdd(&hist[bin], 1);
    }
    __syncthreads();
    if (tid == 0) {
        int acc = 0;
        for (int i = 0; i < 33; ++i) { base[i] = acc; acc += hist[i]; }
    }
    __syncthreads();
    if (tid < B) {
        int rank = atomicAdd(&base[bin], 1);   // sorted-descending rank
        int j;
        if ((B & 255) == 0) {                   // snake across quartile stripes
            int q = rank >> 8, pos = rank & 255;
            j = (q & 1) ? ((q << 8) + 255 - pos) : ((q << 8) + pos);
        } else {
            j = rank;
        }
        blk2item[j] = tid;
    }
}

// Fused A+B step for this group's cell. NJ = ceil(w/4) known at compile time.
template<int NJ>
__device__ __forceinline__ void dmv_step(
    const int w, const int cd, const int gid, const int lg,
    float* __restrict__ sI, float* __restrict__ sF,
    const float* __restrict__ goNC, const float* __restrict__ goHM,
    const float* __restrict__ stHC, const float* __restrict__ stNC,
    const int* __restrict__ th_s, const float* __restrict__ trans_param)
{
    const int cells = 2 * cd;
    if (gid >= cells) return;             // 128 groups >= 126 cells: single trip
    const bool isR = gid < cd;
    const int  sd  = isR ? 1 : 0;
    const int  h   = isR ? gid : (w + gid - cd);
    const int  e   = isR ? (h + w) : (h - w);

    // ---- phase A: I[h][e] = tr + lse over slots k=0..w-1 (ascending memory) ----
    const float tr  = trans_param[(th_s[h] * NMAX + th_s[e]) * 2 + sd] * LOG2E;
    const float gnc = goNC[sd * NMAX + h];
    const float ghm = goHM[sd * NMAX + h];
    const float dcO = stNC[(sd ^ 1) * NMAX + e];
    const int   kG  = isR ? 0 : (w - 1);      // slot where gnc replaces vF+ghm
    const int   kD  = isR ? (w - 1) : 0;      // slot where dcO replaces vC
    const int   pF  = h * LDS_S + (isR ? h : (h - w + 1));   // own F row, +k
    const int   pC  = e * LDS_S + (isR ? (h + 1) : e);       // other F row, +k
    float x[NJ];
    #pragma unroll
    for (int j = 0; j < NJ; ++j) {
        const int k = lg + 4 * j;
        if (j == NJ - 1) {                    // boundary slot: clamp+mask+selects
            const int kc = (k < w) ? k : (w - 1);
            float vF = sF[pF + kc];
            float vC = sF[pC + kc];
            float v = ((k == kG) ? gnc : (vF + ghm)) + ((k == kD) ? dcO : vC);
            x[j] = (k < w) ? v : NEGV;        // masks any garbage/NaN
        } else if (j == 0) {                  // boundary slot (k<=3<=w-2 here)
            float vF = sF[pF + k];
            float vC = sF[pC + k];
            x[j] = ((k == kG) ? gnc : (vF + ghm)) + ((k == kD) ? dcO : vC);
        } else {                              // interior: 4<=k<=w-2, no specials
            x[j] = (sF[pF + k] + ghm) + sF[pC + k];
        }
    }
    float mA = x[0];
    #pragma unroll
    for (int j = 1; j < NJ; ++j) mA = fmaxf(mA, x[j]);
    mA = grp4_max(mA);
    float sA = 0.f;
    #pragma unroll
    for (int j = 0; j < NJ; ++j) sA += EXP2F(x[j] - mA);
    sA = grp4_sum(sA);
    const float ir = mA + LOG2F(sA) + tr;     // group-uniform after DPP
    if (lg == 0) sI[h * LDS_S + e] = ir;

    // ---- phase B: F[h][e] = lse over slots k (ascending) + st_hc ----
    const float dcN = stNC[sd * NMAX + e];
    const float sth = stHC[sd * NMAX + h];
    const int   kS  = isR ? (w - 1) : 0;      // slot where (ir, dcN) substitute
    const int   pI  = h * LDS_S + (isR ? (h + 1) : e);       // own I row, +k
    const int   pG  = (isR ? (h + 1) : e) * LDS_S + e;       // F column e, +k*LDS_S
    float y[NJ];
    #pragma unroll
    for (int j = 0; j < NJ; ++j) {
        const int k = lg + 4 * j;
        if (j == NJ - 1) {
            const int kc = (k < w) ? k : (w - 1);
            float i1 = sI[pI + kc];
            float f1 = sF[pG + kc * LDS_S];
            float v = ((k == kS) ? ir : i1) + ((k == kS) ? dcN : f1);
            y[j] = (k < w) ? v : NEGV;
        } else if (j == 0) {
            float i1 = sI[pI + k];
            float f1 = sF[pG + k * LDS_S];
            y[j] = ((k == kS) ? ir : i1) + ((k == kS) ? dcN : f1);
        } else {
            y[j] = sI[pI + k] + sF[pG + k * LDS_S];
        }
    }
    float mB = y[0];
    #pragma unroll
    for (int j = 1; j < NJ; ++j) mB = fmaxf(mB, y[j]);
    mB = grp4_max(mB);
    float sB = 0.f;
    #pragma unroll
    for (int j = 0; j < NJ; ++j) sB += EXP2F(y[j] - mB);
    sB = grp4_sum(sB);
    if (lg == 0) sF[h * LDS_S + e] = mB + LOG2F(sB) + sth;
}

__global__ __launch_bounds__(BLOCK, 8)
void dmv_inside_kernel(const int* __restrict__ tag,
                       const int* __restrict__ len_arr,
                       const float* __restrict__ root_param,
                       const float* __restrict__ trans_param,
                       const float* __restrict__ dec_param,
                       const int* __restrict__ blk2item,
                       float* __restrict__ out)
{
    __shared__ float sI[NMAX * LDS_S];     // IR upper / IL lower triangle
    __shared__ float sF[NMAX * LDS_S];     // FR upper / FL lower triangle
    __shared__ float goNC[2 * NMAX];       // [0]=L, [1]=R (log2-scaled)
    __shared__ float goHM[2 * NMAX];       // go_hc - st_hc
    __shared__ float stHC[2 * NMAX];
    __shared__ float stNC[2 * NMAX];       // width-0 "diagonal" of F
    __shared__ float root_s[NMAX];
    __shared__ int   th_s[NMAX];

    const int b   = blk2item[blockIdx.x];  // balanced assignment
    const int tid = threadIdx.x;
    const int nl  = len_arr[b];            // 32..64; output depends only on [0,nl)

    if (tid < NMAX) {
        int t = tag[b * NMAX + tid];
        th_s[tid] = t;
        const float* d = dec_param + t * 8;   // [dir][val][dec], L=0 R=1
        goNC[0 * NMAX + tid] = d[0] * LOG2E;
        stNC[0 * NMAX + tid] = d[1] * LOG2E;
        goHM[0 * NMAX + tid] = (d[2] - d[3]) * LOG2E;
        stHC[0 * NMAX + tid] = d[3] * LOG2E;
        goNC[1 * NMAX + tid] = d[4] * LOG2E;
        stNC[1 * NMAX + tid] = d[5] * LOG2E;
        goHM[1 * NMAX + tid] = (d[6] - d[7]) * LOG2E;
        stHC[1 * NMAX + tid] = d[7] * LOG2E;
        root_s[tid]          = root_param[t] * LOG2E;
    }
    __syncthreads();

    const int gid = tid >> 2;      // 0..127 — one DP cell per 4-lane group
    const int lg  = tid & 3;

    for (int w = 1; w < nl; ++w) {
        const int cd = nl - w;
        switch ((w - 1) >> 2) {    // block-uniform scalar dispatch, NJ=ceil(w/4)
        case  0: dmv_step< 1>(w, cd, gid, lg, sI, sF, goNC, goHM, stHC, stNC, th_s, trans_param); break;
        case  1: dmv_step< 2>(w, cd, gid, lg, sI, sF, goNC, goHM, stHC, stNC, th_s, trans_param); break;
        case  2: dmv_step< 3>(w, cd, gid, lg, sI, sF, goNC, goHM, stHC, stNC, th_s, trans_param); break;
        case  3: dmv_step< 4>(w, cd, gid, lg, sI, sF, goNC, goHM, stHC, stNC, th_s, trans_param); break;
        case  4: dmv_step< 5>(w, cd, gid, lg, sI, sF, goNC, goHM, stHC, stNC, th_s, trans_param); break;
        case  5: dmv_step< 6>(w, cd, gid, lg, sI, sF, goNC, goHM, stHC, stNC, th_s, trans_param); break;
        case  6: dmv_step< 7>(w, cd, gid, lg, sI, sF, goNC, goHM, stHC, stNC, th_s, trans_param); break;
        case  7: dmv_step< 8>(w, cd, gid, lg, sI, sF, goNC, goHM, stHC, stNC, th_s, trans_param); break;
        case  8: dmv_step< 9>(w, cd, gid, lg, sI, sF, goNC, goHM, stHC, stNC, th_s, trans_param); break;
        case  9: dmv_step<10>(w, cd, gid, lg, sI, sF, goNC, goHM, stHC, stNC, th_s, trans_param); break;
        case 10: dmv_step<11>(w, cd, gid, lg, sI, sF, goNC, goHM, stHC, stNC, th_s, trans_param); break;
        case 11: dmv_step<12>(w, cd, gid, lg, sI, sF, goNC, goHM, stHC, stNC, th_s, trans_param); break;
        case 12: dmv_step<13>(w, cd, gid, lg, sI, sF, goNC, goHM, stHC, stNC, th_s, trans_param); break;
        case 13: dmv_step<14>(w, cd, gid, lg, sI, sF, goNC, goHM, stHC, stNC, th_s, trans_param); break;
        case 14: dmv_step<15>(w, cd, gid, lg, sI, sF, goNC, goHM, stHC, stNC, th_s, trans_param); break;
        default: dmv_step<16>(w, cd, gid, lg, sI, sF, goNC, goHM, stHC, stNC, th_s, trans_param); break;
        }
        __syncthreads();
    }

    // ---- final: out[b] = ln2 * lse_i( root[i] + FL[i][0] + FR[i][last] ), i<nl ----
    if (tid < 64) {
        const int last = nl - 1;
        float fl0 = (tid == 0)    ? stNC[0 * NMAX + 0]    : sF[tid * LDS_S + 0];
        float fre = (tid == last) ? stNC[1 * NMAX + last] : sF[tid * LDS_S + last];
        float xx  = (tid < nl) ? (root_s[tid] + fl0 + fre) : NEGV;
        float m = xx, s = 1.0f;
        #pragma unroll
        for (int off = 1; off < 64; off <<= 1)
            lse_merge(m, s, __shfl_xor(m, off, 64), __shfl_xor(s, off, 64));
        if (tid == 0) out[b] = (m + LOG2F(s)) * LN2;
    }
}

extern "C" void kernel_launch(void* const* d_in, const int* in_sizes, int n_in,
                              void* d_out, int out_size, void* d_ws, size_t ws_size,
                              hipStream_t stream) {
    // setup_inputs order: id_array, tag_array, len_array, root_param, trans_param, dec_param
    const int*   tag   = (const int*)d_in[1];
    const int*   len_a = (const int*)d_in[2];
    const float* root  = (const float*)d_in[3];
    const float* trans = (const float*)d_in[4];
    const float* dec   = (const float*)d_in[5];
    float* outp = (float*)d_out;
    const int B = in_sizes[2];   // 1024

    int* blk2item = (int*)d_ws;  // B ints

    int sortThreads = (B < 1024) ? ((B + 63) & ~63) : 1024;
    if (sortThreads < 64) sortThreads = 64;
    order_kernel<<<1, sortThreads, 0, stream>>>(len_a, blk2item, B);
    dmv_inside_kernel<<<B, BLOCK, 0, stream>>>(tag, len_a, root, trans, dec,
                                               blk2item, outp);
}

// Round 15
// 61.733 us; speedup vs baseline: 4.1642x; 1.0792x over previous
//
#include <hip/hip_runtime.h>

// DMV inside (log2-space), one block per batch item, 512 threads = 128 groups of 4.
// Structure = R14 (64.2us best): compact cell mapping, ascending-k remap for
// left cells (all streams walk forward, compile-time per-j offsets), single
// template body, local x[]/y[] only, fused A+B, 1 barrier/width.
// NEW: MAX-FREE LSE via f32 trend-shift (R12 algebra, f32 storage).
//  - Charts stored as F' = F + ALPHA*width, I' = I + ALPHA*width (ALPHA=8 ~
//    mean log2 drift/width: trans -6 + go -1 + stop -1). Shift telescopes
//    EXACTLY (every lse's terms share one uniform shift): phase A terms carry
//    ALPHA*(w-1) -> fold +ALPHA into tr; phase B terms carry ALPHA*w -> code
//    unchanged; final subtracts ALPHA*(nl-1). In f32 this is pure
//    reparametrization - zero precision cost.
//  - Residuals bounded (|x'| <~ 60 << 127): exp2 cannot overflow, largest
//    term keeps full f32 relative precision -> the max-subtraction pass is
//    unnecessary: s = sum exp2(x'); val = log2(s)+consts. Per-slot VALU 6->4
//    (A), 5->3 (B); removes both grp4_max DPP pairs; dependent chain ~-30%.
//    (R14 measured VALU-issue-bound: 39us of 64.2 is VALU-active; the max
//    pass was 2/6 of element ops AND the longest serial segment.)
//  - Masked/garbage lanes still NEGV-cndmask'd BEFORE exp2: exp2(-1e9)=0,
//    NaN never reaches exp2. Overflow failure mode is loud (inf->absmax).
//  - 4-lane DPP sum reduce (quad_perm xor1/xor2). 4 blocks/CU, 32 waves/CU.
//  - Load balance: counting-sort + quartile snake (R7).
//  - Spill sentinel: WRITE_SIZE must stay ~22KB (MB-scale => scratch, revert).

#define NEGV   -1000000000.0f
#define NMAX   64
#define LDS_S  69
#define BLOCK  512
#define ALPHA  8.0f

#if __has_builtin(__builtin_amdgcn_exp2f)
#define EXP2F(x) __builtin_amdgcn_exp2f(x)
#else
#define EXP2F(x) __expf((x) * 0.6931471805599453f)
#endif
#if __has_builtin(__builtin_amdgcn_logf)
#define LOG2F(x) __builtin_amdgcn_logf(x)
#else
#define LOG2F(x) (__logf(x) * 1.4426950408889634f)
#endif
#define LOG2E 1.4426950408889634f
#define LN2   0.6931471805599453f

template<int CTRL>
__device__ __forceinline__ float dppf(float v) {
    return __int_as_float(__builtin_amdgcn_update_dpp(
        0, __float_as_int(v), CTRL, 0xF, 0xF, true));
}
__device__ __forceinline__ float grp4_sum(float s) {
    s += dppf<0xB1>(s);    // quad_perm xor 1
    s += dppf<0x4E>(s);    // quad_perm xor 2
    return s;
}

__device__ __forceinline__ void lse_merge(float& m, float& s, float mo, float so) {
    float mn = fmaxf(m, mo);
    s = s * EXP2F(m - mn) + so * EXP2F(mo - mn);
    m = mn;
}

// ---- pre-kernel: counting sort by length (descending) + quartile-snake map ----
__global__ void order_kernel(const int* __restrict__ len_arr,
                             int* __restrict__ blk2item, int B)
{
    __shared__ int hist[33];
    __shared__ int base[33];
    const int tid = threadIdx.x;
    if (tid < 33) hist[tid] = 0;
    __syncthreads();
    int bin = 0;
    if (tid < B) {
        bin = 64 - len_arr[tid];          // 0 = longest
        atomicAdd(&hist[bin], 1);
    }
    __syncthreads();
    if (tid == 0) {
        int acc = 0;
        for (int i = 0; i < 33; ++i) { base[i] = acc; acc += hist[i]; }
    }
    __syncthreads();
    if (tid < B) {
        int rank = atomicAdd(&base[bin], 1);   // sorted-descending rank
        int j;
        if ((B & 255) == 0) {                   // snake across quartile stripes
            int q = rank >> 8, pos = rank & 255;
            j = (q & 1) ? ((q << 8) + 255 - pos) : ((q << 8) + pos);
        } else {
            j = rank;
        }
        blk2item[j] = tid;
    }
}

// Fused A+B step for this group's cell. NJ = ceil(w/4) known at compile time.
template<int NJ>
__device__ __forceinline__ void dmv_step(
    const int w, const int cd, const int gid, const int lg,
    float* __restrict__ sI, float* __restrict__ sF,
    const float* __restrict__ goNC, const float* __restrict__ goHM,
    const float* __restrict__ stHC, const float* __restrict__ stNC,
    const int* __restrict__ th_s, const float* __restrict__ trans_param)
{
    const int cells = 2 * cd;
    if (gid >= cells) return;             // 128 groups >= 126 cells: single trip
    const bool isR = gid < cd;
    const int  sd  = isR ? 1 : 0;
    const int  h   = isR ? gid : (w + gid - cd);
    const int  e   = isR ? (h + w) : (h - w);

    // ---- phase A: I'[h][e] = (tr+ALPHA) + log2( sum_k exp2(x'(k)) ) ----
    // terms x'(k) all carry uniform shift ALPHA*(w-1); +ALPHA folded into tr.
    const float tr  = trans_param[(th_s[h] * NMAX + th_s[e]) * 2 + sd] * LOG2E
                      + ALPHA;
    const float gnc = goNC[sd * NMAX + h];
    const float ghm = goHM[sd * NMAX + h];
    const float dcO = stNC[(sd ^ 1) * NMAX + e];
    const int   kG  = isR ? 0 : (w - 1);      // slot where gnc replaces vF+ghm
    const int   kD  = isR ? (w - 1) : 0;      // slot where dcO replaces vC
    const int   pF  = h * LDS_S + (isR ? h : (h - w + 1));   // own F' row, +k
    const int   pC  = e * LDS_S + (isR ? (h + 1) : e);       // other F' row, +k
    float x[NJ];
    #pragma unroll
    for (int j = 0; j < NJ; ++j) {
        const int k = lg + 4 * j;
        if (j == NJ - 1) {                    // boundary slot: clamp+mask+selects
            const int kc = (k < w) ? k : (w - 1);
            float vF = sF[pF + kc];
            float vC = sF[pC + kc];
            float v = ((k == kG) ? gnc : (vF + ghm)) + ((k == kD) ? dcO : vC);
            x[j] = (k < w) ? v : NEGV;        // masks garbage/NaN; exp2(NEGV)=0
        } else if (j == 0) {                  // boundary slot (k<=3<=w-2 here)
            float vF = sF[pF + k];
            float vC = sF[pC + k];
            x[j] = ((k == kG) ? gnc : (vF + ghm)) + ((k == kD) ? dcO : vC);
        } else {                              // interior: 4<=k<=w-2, no specials
            x[j] = (sF[pF + k] + ghm) + sF[pC + k];
        }
    }
    float sA = 0.f;
    #pragma unroll
    for (int j = 0; j < NJ; ++j) sA += EXP2F(x[j]);   // max-free: |x'| bounded
    sA = grp4_sum(sA);
    const float ir = LOG2F(sA) + tr;          // group-uniform after DPP (= I')
    if (lg == 0) sI[h * LDS_S + e] = ir;

    // ---- phase B: F'[h][e] = log2( sum_k exp2(y'(k)) ) + st_hc ----
    // terms y'(k) all carry uniform shift ALPHA*w — consistent with storage.
    const float dcN = stNC[sd * NMAX + e];
    const float sth = stHC[sd * NMAX + h];
    const int   kS  = isR ? (w - 1) : 0;      // slot where (ir, dcN) substitute
    const int   pI  = h * LDS_S + (isR ? (h + 1) : e);       // own I' row, +k
    const int   pG  = (isR ? (h + 1) : e) * LDS_S + e;       // F' column e, +k*LDS_S
    float y[NJ];
    #pragma unroll
    for (int j = 0; j < NJ; ++j) {
        const int k = lg + 4 * j;
        if (j == NJ - 1) {
            const int kc = (k < w) ? k : (w - 1);
            float i1 = sI[pI + kc];
            float f1 = sF[pG + kc * LDS_S];
            float v = ((k == kS) ? ir : i1) + ((k == kS) ? dcN : f1);
            y[j] = (k < w) ? v : NEGV;
        } else if (j == 0) {
            float i1 = sI[pI + k];
            float f1 = sF[pG + k * LDS_S];
            y[j] = ((k == kS) ? ir : i1) + ((k == kS) ? dcN : f1);
        } else {
            y[j] = sI[pI + k] + sF[pG + k * LDS_S];
        }
    }
    float sB = 0.f;
    #pragma unroll
    for (int j = 0; j < NJ; ++j) sB += EXP2F(y[j]);
    sB = grp4_sum(sB);
    if (lg == 0) sF[h * LDS_S + e] = LOG2F(sB) + sth;
}

__global__ __launch_bounds__(BLOCK, 8)
void dmv_inside_kernel(const int* __restrict__ tag,
                       const int* __restrict__ len_arr,
                       const float* __restrict__ root_param,
                       const float* __restrict__ trans_param,
                       const float* __restrict__ dec_param,
                       const int* __restrict__ blk2item,
                       float* __restrict__ out)
{
    __shared__ float sI[NMAX * LDS_S];     // I' (trend-removed) triangles, f32
    __shared__ float sF[NMAX * LDS_S];     // F' triangles, f32
    __shared__ float goNC[2 * NMAX];       // [0]=L, [1]=R (log2-scaled)
    __shared__ float goHM[2 * NMAX];       // go_hc - st_hc
    __shared__ float stHC[2 * NMAX];
    __shared__ float stNC[2 * NMAX];       // width-0 "diagonal" of F (shift 0)
    __shared__ float root_s[NMAX];
    __shared__ int   th_s[NMAX];

    const int b   = blk2item[blockIdx.x];  // balanced assignment
    const int tid = threadIdx.x;
    const int nl  = len_arr[b];            // 32..64; output depends only on [0,nl)

    if (tid < NMAX) {
        int t = tag[b * NMAX + tid];
        th_s[tid] = t;
        const float* d = dec_param + t * 8;   // [dir][val][dec], L=0 R=1
        goNC[0 * NMAX + tid] = d[0] * LOG2E;
        stNC[0 * NMAX + tid] = d[1] * LOG2E;
        goHM[0 * NMAX + tid] = (d[2] - d[3]) * LOG2E;
        stHC[0 * NMAX + tid] = d[3] * LOG2E;
        goNC[1 * NMAX + tid] = d[4] * LOG2E;
        stNC[1 * NMAX + tid] = d[5] * LOG2E;
        goHM[1 * NMAX + tid] = (d[6] - d[7]) * LOG2E;
        stHC[1 * NMAX + tid] = d[7] * LOG2E;
        root_s[tid]          = root_param[t] * LOG2E;
    }
    __syncthreads();

    const int gid = tid >> 2;      // 0..127 — one DP cell per 4-lane group
    const int lg  = tid & 3;

    for (int w = 1; w < nl; ++w) {
        const int cd = nl - w;
        switch ((w - 1) >> 2) {    // block-uniform scalar dispatch, NJ=ceil(w/4)
        case  0: dmv_step< 1>(w, cd, gid, lg, sI, sF, goNC, goHM, stHC, stNC, th_s, trans_param); break;
        case  1: dmv_step< 2>(w, cd, gid, lg, sI, sF, goNC, goHM, stHC, stNC, th_s, trans_param); break;
        case  2: dmv_step< 3>(w, cd, gid, lg, sI, sF, goNC, goHM, stHC, stNC, th_s, trans_param); break;
        case  3: dmv_step< 4>(w, cd, gid, lg, sI, sF, goNC, goHM, stHC, stNC, th_s, trans_param); break;
        case  4: dmv_step< 5>(w, cd, gid, lg, sI, sF, goNC, goHM, stHC, stNC, th_s, trans_param); break;
        case  5: dmv_step< 6>(w, cd, gid, lg, sI, sF, goNC, goHM, stHC, stNC, th_s, trans_param); break;
        case  6: dmv_step< 7>(w, cd, gid, lg, sI, sF, goNC, goHM, stHC, stNC, th_s, trans_param); break;
        case  7: dmv_step< 8>(w, cd, gid, lg, sI, sF, goNC, goHM, stHC, stNC, th_s, trans_param); break;
        case  8: dmv_step< 9>(w, cd, gid, lg, sI, sF, goNC, goHM, stHC, stNC, th_s, trans_param); break;
        case  9: dmv_step<10>(w, cd, gid, lg, sI, sF, goNC, goHM, stHC, stNC, th_s, trans_param); break;
        case 10: dmv_step<11>(w, cd, gid, lg, sI, sF, goNC, goHM, stHC, stNC, th_s, trans_param); break;
        case 11: dmv_step<12>(w, cd, gid, lg, sI, sF, goNC, goHM, stHC, stNC, th_s, trans_param); break;
        case 12: dmv_step<13>(w, cd, gid, lg, sI, sF, goNC, goHM, stHC, stNC, th_s, trans_param); break;
        case 13: dmv_step<14>(w, cd, gid, lg, sI, sF, goNC, goHM, stHC, stNC, th_s, trans_param); break;
        case 14: dmv_step<15>(w, cd, gid, lg, sI, sF, goNC, goHM, stHC, stNC, th_s, trans_param); break;
        default: dmv_step<16>(w, cd, gid, lg, sI, sF, goNC, goHM, stHC, stNC, th_s, trans_param); break;
        }
        __syncthreads();
    }

    // ---- final: stored fl0'+fre' shift uniformly by ALPHA*(nl-1) ----
    // out[b] = ln2 * ( lse_i( root[i] + FL'[i][0] + FR'[i][last] ) - ALPHA*last )
    if (tid < 64) {
        const int last = nl - 1;
        float fl0 = (tid == 0)    ? stNC[0 * NMAX + 0]    : sF[tid * LDS_S + 0];
        float fre = (tid == last) ? stNC[1 * NMAX + last] : sF[tid * LDS_S + last];
        float xx  = (tid < nl) ? (root_s[tid] + fl0 + fre) : NEGV;
        float m = xx, s = 1.0f;
        #pragma unroll
        for (int off = 1; off < 64; off <<= 1)
            lse_merge(m, s, __shfl_xor(m, off, 64), __shfl_xor(s, off, 64));
        if (tid == 0) out[b] = (m + LOG2F(s) - ALPHA * last) * LN2;
    }
}

extern "C" void kernel_launch(void* const* d_in, const int* in_sizes, int n_in,
                              void* d_out, int out_size, void* d_ws, size_t ws_size,
                              hipStream_t stream) {
    // setup_inputs order: id_array, tag_array, len_array, root_param, trans_param, dec_param
    const int*   tag   = (const int*)d_in[1];
    const int*   len_a = (const int*)d_in[2];
    const float* root  = (const float*)d_in[3];
    const float* trans = (const float*)d_in[4];
    const float* dec   = (const float*)d_in[5];
    float* outp = (float*)d_out;
    const int B = in_sizes[2];   // 1024

    int* blk2item = (int*)d_ws;  // B ints

    int sortThreads = (B < 1024) ? ((B + 63) & ~63) : 1024;
    if (sortThreads < 64) sortThreads = 64;
    order_kernel<<<1, sortThreads, 0, stream>>>(len_a, blk2item, B);
    dmv_inside_kernel<<<B, BLOCK, 0, stream>>>(tag, len_a, root, trans, dec,
                                               blk2item, outp);
}

// Round 16
// 57.602 us; speedup vs baseline: 4.4629x; 1.0717x over previous
//
#include <hip/hip_runtime.h>

// DMV inside — LINEAR-DOMAIN SUM-PRODUCT with trend scaling. One block per
// batch item, 512 threads = 128 groups of 4.
// Structure = R14/R15 (58.6us best): compact cell mapping, ascending-k remap
// (all streams walk forward, compile-time per-j offsets), single template
// body, local accumulators only, fused A+B, 1 barrier/width.
// NEW: charts stored LINEAR: F'' = exp2(F + ALPHA*width), I'' likewise.
//  - R15 proved (absmax 0.0) the trend-shifted residuals live in a bounded
//    exp2-safe window; so drop log space entirely: lse -> sum, + -> *.
//    Interior slot: 1 fma (was add+add+exp2+add, exp2 at 1/4 rate).
//    Per-cell gm multiplier hoisted: total = fma(gm, s_int, s_bnd).
//    log2/exp2 leave the inner loop (1 exp2/cell for tr_lin; 1 log2/item).
//  - Shift algebra telescopes exactly (same as R15): phase A product carries
//    2^(ALPHA*(w-1)) -> tr_lin = exp2(tr*LOG2E + ALPHA); phase B carries
//    2^(ALPHA*w) consistent with storage; final divides by 2^(ALPHA*last).
//  - Precision: sums of <=64 balanced positive f32 terms over 63 levels ->
//    rel err ~1e-5 -> ~2e-5 in output log (threshold 5.72). Linear values in
//    2^(+-40) << f32 range; failure mode is loud (0/inf), not silent.
//  - Masking: select-AFTER-compute ((k<w)?v:0) so garbage/NaN LDS reads are
//    discarded before accumulation — exactly R15's discipline.
//  - 4-lane DPP sum reduce. 4 blocks/CU, 32 waves/CU. Snake balance (R7).
//  - Spill sentinel: WRITE_SIZE ~22KB (MB-scale => scratch, revert).

#define NEGV   -1000000000.0f
#define NMAX   64
#define LDS_S  69
#define BLOCK  512
#define ALPHA  8.0f

#if __has_builtin(__builtin_amdgcn_exp2f)
#define EXP2F(x) __builtin_amdgcn_exp2f(x)
#else
#define EXP2F(x) __expf((x) * 0.6931471805599453f)
#endif
#if __has_builtin(__builtin_amdgcn_logf)
#define LOG2F(x) __builtin_amdgcn_logf(x)
#else
#define LOG2F(x) (__logf(x) * 1.4426950408889634f)
#endif
#define LOG2E 1.4426950408889634f
#define LN2   0.6931471805599453f

template<int CTRL>
__device__ __forceinline__ float dppf(float v) {
    return __int_as_float(__builtin_amdgcn_update_dpp(
        0, __float_as_int(v), CTRL, 0xF, 0xF, true));
}
__device__ __forceinline__ float grp4_sum(float s) {
    s += dppf<0xB1>(s);    // quad_perm xor 1
    s += dppf<0x4E>(s);    // quad_perm xor 2
    return s;
}

// ---- pre-kernel: counting sort by length (descending) + quartile-snake map ----
__global__ void order_kernel(const int* __restrict__ len_arr,
                             int* __restrict__ blk2item, int B)
{
    __shared__ int hist[33];
    __shared__ int base[33];
    const int tid = threadIdx.x;
    if (tid < 33) hist[tid] = 0;
    __syncthreads();
    int bin = 0;
    if (tid < B) {
        bin = 64 - len_arr[tid];          // 0 = longest
        atomicAdd(&hist[bin], 1);
    }
    __syncthreads();
    if (tid == 0) {
        int acc = 0;
        for (int i = 0; i < 33; ++i) { base[i] = acc; acc += hist[i]; }
    }
    __syncthreads();
    if (tid < B) {
        int rank = atomicAdd(&base[bin], 1);   // sorted-descending rank
        int j;
        if ((B & 255) == 0) {                   // snake across quartile stripes
            int q = rank >> 8, pos = rank & 255;
            j = (q & 1) ? ((q << 8) + 255 - pos) : ((q << 8) + pos);
        } else {
            j = rank;
        }
        blk2item[j] = tid;
    }
}

// Fused A+B step for this group's cell. NJ = ceil(w/4) known at compile time.
// All chart values LINEAR (trend-scaled). Params pre-exponentiated.
template<int NJ>
__device__ __forceinline__ void dmv_step(
    const int w, const int cd, const int gid, const int lg,
    float* __restrict__ sI, float* __restrict__ sF,
    const float* __restrict__ goNCl, const float* __restrict__ goHMl,
    const float* __restrict__ stHCl, const float* __restrict__ stNCl,
    const int* __restrict__ th_s, const float* __restrict__ trans_param)
{
    const int cells = 2 * cd;
    if (gid >= cells) return;             // 128 groups >= 126 cells: single trip
    const bool isR = gid < cd;
    const int  sd  = isR ? 1 : 0;
    const int  h   = isR ? gid : (w + gid - cd);
    const int  e   = isR ? (h + w) : (h - w);

    // ---- phase A: I''[h][e] = tr_lin * sum_k term(k) ----
    const float trl = EXP2F(trans_param[(th_s[h] * NMAX + th_s[e]) * 2 + sd]
                            * LOG2E + ALPHA);        // carries 2^ALPHA shift
    const float gnc = goNCl[sd * NMAX + h];
    const float gm  = goHMl[sd * NMAX + h];          // linear (go_hc - st_hc)
    const float dcO = stNCl[(sd ^ 1) * NMAX + e];
    const int   kG  = isR ? 0 : (w - 1);      // slot where gnc replaces vF*gm
    const int   kD  = isR ? (w - 1) : 0;      // slot where dcO replaces vC
    const int   pF  = h * LDS_S + (isR ? h : (h - w + 1));   // own F'' row, +k
    const int   pC  = e * LDS_S + (isR ? (h + 1) : e);       // other F'' row, +k
    float sInt = 0.f, sBnd = 0.f;
    #pragma unroll
    for (int j = 0; j < NJ; ++j) {
        const int k = lg + 4 * j;
        if (j == NJ - 1) {                    // boundary slot: clamp+mask+selects
            const int kc = (k < w) ? k : (w - 1);
            float vF = sF[pF + kc];
            float vC = sF[pC + kc];
            float v  = ((k == kG) ? gnc : (vF * gm)) * ((k == kD) ? dcO : vC);
            sBnd += (k < w) ? v : 0.f;        // select AFTER compute: kills NaN
        } else if (j == 0) {                  // boundary slot (k<=3<=w-2 here)
            float vF = sF[pF + k];
            float vC = sF[pC + k];
            sBnd += ((k == kG) ? gnc : (vF * gm)) * ((k == kD) ? dcO : vC);
        } else {                              // interior: 4<=k<=w-2, no specials
            sInt = fmaf(sF[pF + k], sF[pC + k], sInt);
        }
    }
    float sA = grp4_sum(fmaf(gm, sInt, sBnd));
    const float ir = trl * sA;                // group-uniform after DPP (= I'')
    if (lg == 0) sI[h * LDS_S + e] = ir;

    // ---- phase B: F''[h][e] = st_hc_lin * sum_k term(k) ----
    const float dcN  = stNCl[sd * NMAX + e];
    const float sthl = stHCl[sd * NMAX + h];
    const int   kS   = isR ? (w - 1) : 0;     // slot where (ir, dcN) substitute
    const int   pI   = h * LDS_S + (isR ? (h + 1) : e);      // own I'' row, +k
    const int   pG   = (isR ? (h + 1) : e) * LDS_S + e;      // F'' col e, +k*LDS_S
    float tInt = 0.f, tBnd = 0.f;
    #pragma unroll
    for (int j = 0; j < NJ; ++j) {
        const int k = lg + 4 * j;
        if (j == NJ - 1) {
            const int kc = (k < w) ? k : (w - 1);
            float i1 = sI[pI + kc];
            float f1 = sF[pG + kc * LDS_S];
            float v  = ((k == kS) ? ir : i1) * ((k == kS) ? dcN : f1);
            tBnd += (k < w) ? v : 0.f;
        } else if (j == 0) {
            float i1 = sI[pI + k];
            float f1 = sF[pG + k * LDS_S];
            tBnd += ((k == kS) ? ir : i1) * ((k == kS) ? dcN : f1);
        } else {
            tInt = fmaf(sI[pI + k], sF[pG + k * LDS_S], tInt);
        }
    }
    float sB = grp4_sum(tInt + tBnd);
    if (lg == 0) sF[h * LDS_S + e] = sthl * sB;
}

__global__ __launch_bounds__(BLOCK, 8)
void dmv_inside_kernel(const int* __restrict__ tag,
                       const int* __restrict__ len_arr,
                       const float* __restrict__ root_param,
                       const float* __restrict__ trans_param,
                       const float* __restrict__ dec_param,
                       const int* __restrict__ blk2item,
                       float* __restrict__ out)
{
    __shared__ float sI[NMAX * LDS_S];     // I'' (linear, trend-scaled)
    __shared__ float sF[NMAX * LDS_S];     // F'' (linear, trend-scaled)
    __shared__ float goNCl[2 * NMAX];      // linear params; [0]=L, [1]=R
    __shared__ float goHMl[2 * NMAX];      // exp2(go_hc - st_hc)
    __shared__ float stHCl[2 * NMAX];
    __shared__ float stNCl[2 * NMAX];      // width-0 "diagonal" of F'' (shift 0)
    __shared__ float root_l[NMAX];         // linear root
    __shared__ int   th_s[NMAX];

    const int b   = blk2item[blockIdx.x];  // balanced assignment
    const int tid = threadIdx.x;
    const int nl  = len_arr[b];            // 32..64; output depends only on [0,nl)

    if (tid < NMAX) {
        int t = tag[b * NMAX + tid];
        th_s[tid] = t;
        const float* d = dec_param + t * 8;   // [dir][val][dec], L=0 R=1
        goNCl[0 * NMAX + tid] = EXP2F(d[0] * LOG2E);
        stNCl[0 * NMAX + tid] = EXP2F(d[1] * LOG2E);
        goHMl[0 * NMAX + tid] = EXP2F((d[2] - d[3]) * LOG2E);
        stHCl[0 * NMAX + tid] = EXP2F(d[3] * LOG2E);
        goNCl[1 * NMAX + tid] = EXP2F(d[4] * LOG2E);
        stNCl[1 * NMAX + tid] = EXP2F(d[5] * LOG2E);
        goHMl[1 * NMAX + tid] = EXP2F((d[6] - d[7]) * LOG2E);
        stHCl[1 * NMAX + tid] = EXP2F(d[7] * LOG2E);
        root_l[tid]           = EXP2F(root_param[t] * LOG2E);
    }
    __syncthreads();

    const int gid = tid >> 2;      // 0..127 — one DP cell per 4-lane group
    const int lg  = tid & 3;

    for (int w = 1; w < nl; ++w) {
        const int cd = nl - w;
        switch ((w - 1) >> 2) {    // block-uniform scalar dispatch, NJ=ceil(w/4)
        case  0: dmv_step< 1>(w, cd, gid, lg, sI, sF, goNCl, goHMl, stHCl, stNCl, th_s, trans_param); break;
        case  1: dmv_step< 2>(w, cd, gid, lg, sI, sF, goNCl, goHMl, stHCl, stNCl, th_s, trans_param); break;
        case  2: dmv_step< 3>(w, cd, gid, lg, sI, sF, goNCl, goHMl, stHCl, stNCl, th_s, trans_param); break;
        case  3: dmv_step< 4>(w, cd, gid, lg, sI, sF, goNCl, goHMl, stHCl, stNCl, th_s, trans_param); break;
        case  4: dmv_step< 5>(w, cd, gid, lg, sI, sF, goNCl, goHMl, stHCl, stNCl, th_s, trans_param); break;
        case  5: dmv_step< 6>(w, cd, gid, lg, sI, sF, goNCl, goHMl, stHCl, stNCl, th_s, trans_param); break;
        case  6: dmv_step< 7>(w, cd, gid, lg, sI, sF, goNCl, goHMl, stHCl, stNCl, th_s, trans_param); break;
        case  7: dmv_step< 8>(w, cd, gid, lg, sI, sF, goNCl, goHMl, stHCl, stNCl, th_s, trans_param); break;
        case  8: dmv_step< 9>(w, cd, gid, lg, sI, sF, goNCl, goHMl, stHCl, stNCl, th_s, trans_param); break;
        case  9: dmv_step<10>(w, cd, gid, lg, sI, sF, goNCl, goHMl, stHCl, stNCl, th_s, trans_param); break;
        case 10: dmv_step<11>(w, cd, gid, lg, sI, sF, goNCl, goHMl, stHCl, stNCl, th_s, trans_param); break;
        case 11: dmv_step<12>(w, cd, gid, lg, sI, sF, goNCl, goHMl, stHCl, stNCl, th_s, trans_param); break;
        case 12: dmv_step<13>(w, cd, gid, lg, sI, sF, goNCl, goHMl, stHCl, stNCl, th_s, trans_param); break;
        case 13: dmv_step<14>(w, cd, gid, lg, sI, sF, goNCl, goHMl, stHCl, stNCl, th_s, trans_param); break;
        case 14: dmv_step<15>(w, cd, gid, lg, sI, sF, goNCl, goHMl, stHCl, stNCl, th_s, trans_param); break;
        default: dmv_step<16>(w, cd, gid, lg, sI, sF, goNCl, goHMl, stHCl, stNCl, th_s, trans_param); break;
        }
        __syncthreads();
    }

    // ---- final (linear): out = ln2*(log2( sum_i root_l*FL''*FR'' ) - ALPHA*last)
    if (tid < 64) {
        const int last = nl - 1;
        float fl0 = (tid == 0)    ? stNCl[0 * NMAX + 0]    : sF[tid * LDS_S + 0];
        float fre = (tid == last) ? stNCl[1 * NMAX + last] : sF[tid * LDS_S + last];
        float xx  = (tid < nl) ? (root_l[tid] * fl0 * fre) : 0.f;  // select kills NaN
        #pragma unroll
        for (int off = 1; off < 64; off <<= 1)
            xx += __shfl_xor(xx, off, 64);
        if (tid == 0) out[b] = (LOG2F(xx) - ALPHA * last) * LN2;
    }
}

extern "C" void kernel_launch(void* const* d_in, const int* in_sizes, int n_in,
                              void* d_out, int out_size, void* d_ws, size_t ws_size,
                              hipStream_t stream) {
    // setup_inputs order: id_array, tag_array, len_array, root_param, trans_param, dec_param
    const int*   tag   = (const int*)d_in[1];
    const int*   len_a = (const int*)d_in[2];
    const float* root  = (const float*)d_in[3];
    const float* trans = (const float*)d_in[4];
    const float* dec   = (const float*)d_in[5];
    float* outp = (float*)d_out;
    const int B = in_sizes[2];   // 1024

    int* blk2item = (int*)d_ws;  // B ints

    int sortThreads = (B < 1024) ? ((B + 63) & ~63) : 1024;
    if (sortThreads < 64) sortThreads = 64;
    order_kernel<<<1, sortThreads, 0, stream>>>(len_a, blk2item, B);
    dmv_inside_kernel<<<B, BLOCK, 0, stream>>>(tag, len_a, root, trans, dec,
                                               blk2item, outp);
}

// Round 17
// 55.111 us; speedup vs baseline: 4.6646x; 1.0452x over previous
//
#include <hip/hip_runtime.h>

// DMV inside — linear-domain sum-product, PAIRED SPANS. One block per batch
// item, 512 threads = 64 groups of 8; group g owns span (h=g, e=h+w) and
// computes BOTH direction cells.
//  - R16 proved linear-domain (trend-scaled charts F''=exp2(F+ALPHA*w)) is
//    exact-enough (absmax 0.0) and VALU-cheap. Remaining floor = DS stream.
//  - PAIRING (linear makes it work; R13's log-space attempt doubled VALU):
//    both cells' phase A read the SAME segments FR[h][h..e-1], FL[e][h+1..e];
//    interior term for right = gmR*(vF*vC), left = gmL*(vF*vC) -> ONE shared
//    fma/slot, gm folded after: aR=fma(gmR,sInt,bndR), aL=fma(gmL,sInt,bndL).
//    Phase-A DS reads and fmas HALVE; phase B unchanged; total DS -25%.
//  - Boundary selects only in 2 slots (j==0: k=0 specials; j==NJ-1: k=w-1 +
//    tail mask). Select-AFTER-compute discards garbage/NaN (diag slots
//    unwritten). Width-w I/F used via registers irR/irL within the step; no
//    cross-group width-w reads -> no write race.
//  - Ascending addressing, compile-time per-j offsets (8 dwords apart ->
//    ds_read2-mergeable), single template body, scalars only (spill-safe).
//  - 8-lane DPP reduce (quad_perm xor1/xor2 + row_half_mirror). 4 blocks/CU.
//  - Load balance: counting-sort + quartile snake (R7).
//  - Spill sentinel: WRITE_SIZE ~22KB (MB-scale => scratch, revert to R16).

#define NEGV   -1000000000.0f
#define NMAX   64
#define LDS_S  69
#define BLOCK  512
#define ALPHA  8.0f

#if __has_builtin(__builtin_amdgcn_exp2f)
#define EXP2F(x) __builtin_amdgcn_exp2f(x)
#else
#define EXP2F(x) __expf((x) * 0.6931471805599453f)
#endif
#if __has_builtin(__builtin_amdgcn_logf)
#define LOG2F(x) __builtin_amdgcn_logf(x)
#else
#define LOG2F(x) (__logf(x) * 1.4426950408889634f)
#endif
#define LOG2E 1.4426950408889634f
#define LN2   0.6931471805599453f

template<int CTRL>
__device__ __forceinline__ float dppf(float v) {
    return __int_as_float(__builtin_amdgcn_update_dpp(
        0, __float_as_int(v), CTRL, 0xF, 0xF, true));
}
__device__ __forceinline__ float grp8_sum(float s) {
    s += dppf<0xB1>(s);     // quad_perm xor 1
    s += dppf<0x4E>(s);     // quad_perm xor 2
    s += dppf<0x141>(s);    // row_half_mirror (joins quads in 8-lane group)
    return s;
}

// ---- pre-kernel: counting sort by length (descending) + quartile-snake map ----
__global__ void order_kernel(const int* __restrict__ len_arr,
                             int* __restrict__ blk2item, int B)
{
    __shared__ int hist[33];
    __shared__ int base[33];
    const int tid = threadIdx.x;
    if (tid < 33) hist[tid] = 0;
    __syncthreads();
    int bin = 0;
    if (tid < B) {
        bin = 64 - len_arr[tid];          // 0 = longest
        atomicAdd(&hist[bin], 1);
    }
    __syncthreads();
    if (tid == 0) {
        int acc = 0;
        for (int i = 0; i < 33; ++i) { base[i] = acc; acc += hist[i]; }
    }
    __syncthreads();
    if (tid < B) {
        int rank = atomicAdd(&base[bin], 1);   // sorted-descending rank
        int j;
        if ((B & 255) == 0) {                   // snake across quartile stripes
            int q = rank >> 8, pos = rank & 255;
            j = (q & 1) ? ((q << 8) + 255 - pos) : ((q << 8) + pos);
        } else {
            j = rank;
        }
        blk2item[j] = tid;
    }
}

// Paired fused A+B step for span (h=gid, e=h+w). NJ = ceil(w/8), compile-time.
// All chart values LINEAR (trend-scaled). Params pre-exponentiated.
template<int NJ>
__device__ __forceinline__ void dmv_step(
    const int w, const int cd, const int gid, const int lg,
    float* __restrict__ sI, float* __restrict__ sF,
    const float* __restrict__ goNCl, const float* __restrict__ goHMl,
    const float* __restrict__ stHCl, const float* __restrict__ stNCl,
    const int* __restrict__ th_s, const float* __restrict__ trans_param)
{
    if (gid >= cd) return;
    const int h = gid, e = h + w;

    const int thh = th_s[h], the = th_s[e];
    const float trlR = EXP2F(trans_param[(thh * NMAX + the) * 2 + 1] * LOG2E + ALPHA);
    const float trlL = EXP2F(trans_param[(the * NMAX + thh) * 2 + 0] * LOG2E + ALPHA);
    const float gncR = goNCl[NMAX + h], gmR = goHMl[NMAX + h];
    const float gncL = goNCl[e],        gmL = goHMl[e];
    const float dcR  = stNCl[NMAX + h];   // FR[h][h] width-0 diag
    const float dcL  = stNCl[e];          // FL[e][e]
    const float dcRe = stNCl[NMAX + e];   // FR[e][e] (B right endpoint)
    const float dcLh = stNCl[h];          // FL[h][h] (B left endpoint)

    // ---- phase A (shared streams): vF = FR[h][h+k], vC = FL[e][h+1+k] ----
    // right term(k) = ((k==0)? gncR : vF*gmR) * ((k==w-1)? dcL : vC)
    // left  term(k) = ((k==w-1)? gncL : vC*gmL) * ((k==0)? dcR : vF)
    // interior (1<=k<=w-2): gmR*(vF*vC) and gmL*(vF*vC) — shared product.
    const int pF = h * LDS_S + h;        // +k
    const int pC = e * LDS_S + h + 1;    // +k
    float sInt = 0.f, bndR = 0.f, bndL = 0.f;
    #pragma unroll
    for (int j = 0; j < NJ; ++j) {
        const int k = lg + 8 * j;
        if (j == NJ - 1) {                    // top boundary: clamp+mask+selects
            const int kc = (k < w) ? k : (w - 1);
            float vF = sF[pF + kc];
            float vC = sF[pC + kc];
            float tR = ((k == 0) ? gncR : vF * gmR) * ((k == w - 1) ? dcL : vC);
            float tL = ((k == w - 1) ? gncL : vC * gmL) * ((k == 0) ? dcR : vF);
            bndR += (k < w) ? tR : 0.f;       // select AFTER compute: kills NaN
            bndL += (k < w) ? tL : 0.f;
        } else if (j == 0) {                  // bottom boundary (k<=7<=w-2 here)
            float vF = sF[pF + k];
            float vC = sF[pC + k];
            bndR += ((k == 0) ? gncR : vF * gmR) * vC;
            bndL += (vC * gmL) * ((k == 0) ? dcR : vF);
        } else {                              // interior: shared fma
            sInt = fmaf(sF[pF + k], sF[pC + k], sInt);
        }
    }
    const float aR = grp8_sum(fmaf(gmR, sInt, bndR));
    const float aL = grp8_sum(fmaf(gmL, sInt, bndL));
    const float irR = trlR * aR;              // group-uniform after DPP
    const float irL = trlL * aL;
    if (lg == 0) sI[h * LDS_S + e] = irR;
    if (lg == 1) sI[e * LDS_S + h] = irL;

    // ---- phase B (independent streams):
    // right: sum_k I_R[h][h+1+k] * F[h+1+k][e], k=0..w-1 (k=w-1 -> irR*dcRe)
    // left:  sum_m I_L[e][h+m]   * F[h+m][h],   m=0..w-1 (m=0   -> irL*dcLh)
    const int pIR = h * LDS_S + h + 1;    // +k
    const int pGR = (h + 1) * LDS_S + e;  // +k*LDS_S
    const int pIL = e * LDS_S + h;        // +m
    const int pGL = h * LDS_S + h;        // +m*LDS_S
    float accR = 0.f, accL = 0.f;
    #pragma unroll
    for (int j = 0; j < NJ; ++j) {
        const int k = lg + 8 * j;
        if (j == NJ - 1) {
            const int kc = (k < w) ? k : (w - 1);
            float i1 = sI[pIR + kc];
            float f1 = sF[pGR + kc * LDS_S];
            float i2 = sI[pIL + kc];
            float f2 = sF[pGL + kc * LDS_S];
            float tR = ((k == w - 1) ? irR : i1) * ((k == w - 1) ? dcRe : f1);
            float tL = ((k == 0) ? irL : i2) * ((k == 0) ? dcLh : f2);
            accR += (k < w) ? tR : 0.f;
            accL += (k < w) ? tL : 0.f;
        } else if (j == 0) {                  // k<=7<w-1: right has no special
            float i1 = sI[pIR + k];
            float f1 = sF[pGR + k * LDS_S];
            float i2 = sI[pIL + k];
            float f2 = sF[pGL + k * LDS_S];
            accR = fmaf(i1, f1, accR);
            accL += ((k == 0) ? irL : i2) * ((k == 0) ? dcLh : f2);
        } else {
            accR = fmaf(sI[pIR + k], sF[pGR + k * LDS_S], accR);
            accL = fmaf(sI[pIL + k], sF[pGL + k * LDS_S], accL);
        }
    }
    const float bR = grp8_sum(accR);
    const float bL = grp8_sum(accL);
    if (lg == 0) sF[h * LDS_S + e] = stHCl[NMAX + h] * bR;
    if (lg == 1) sF[e * LDS_S + h] = stHCl[e] * bL;
}

__global__ __launch_bounds__(BLOCK, 8)
void dmv_inside_kernel(const int* __restrict__ tag,
                       const int* __restrict__ len_arr,
                       const float* __restrict__ root_param,
                       const float* __restrict__ trans_param,
                       const float* __restrict__ dec_param,
                       const int* __restrict__ blk2item,
                       float* __restrict__ out)
{
    __shared__ float sI[NMAX * LDS_S];     // I'' (linear, trend-scaled)
    __shared__ float sF[NMAX * LDS_S];     // F'' (linear, trend-scaled)
    __shared__ float goNCl[2 * NMAX];      // linear params; [0]=L, [1]=R
    __shared__ float goHMl[2 * NMAX];      // exp2(go_hc - st_hc)
    __shared__ float stHCl[2 * NMAX];
    __shared__ float stNCl[2 * NMAX];      // width-0 "diagonal" of F'' (shift 0)
    __shared__ float root_l[NMAX];         // linear root
    __shared__ int   th_s[NMAX];

    const int b   = blk2item[blockIdx.x];  // balanced assignment
    const int tid = threadIdx.x;
    const int nl  = len_arr[b];            // 32..64; output depends only on [0,nl)

    if (tid < NMAX) {
        int t = tag[b * NMAX + tid];
        th_s[tid] = t;
        const float* d = dec_param + t * 8;   // [dir][val][dec], L=0 R=1
        goNCl[0 * NMAX + tid] = EXP2F(d[0] * LOG2E);
        stNCl[0 * NMAX + tid] = EXP2F(d[1] * LOG2E);
        goHMl[0 * NMAX + tid] = EXP2F((d[2] - d[3]) * LOG2E);
        stHCl[0 * NMAX + tid] = EXP2F(d[3] * LOG2E);
        goNCl[1 * NMAX + tid] = EXP2F(d[4] * LOG2E);
        stNCl[1 * NMAX + tid] = EXP2F(d[5] * LOG2E);
        goHMl[1 * NMAX + tid] = EXP2F((d[6] - d[7]) * LOG2E);
        stHCl[1 * NMAX + tid] = EXP2F(d[7] * LOG2E);
        root_l[tid]           = EXP2F(root_param[t] * LOG2E);
    }
    __syncthreads();

    const int gid = tid >> 3;      // 0..63 — one span (two cells) per group
    const int lg  = tid & 7;

    for (int w = 1; w < nl; ++w) {
        const int cd = nl - w;     // spans this step (<= 63 <= 64 groups)
        switch ((w - 1) >> 3) {    // block-uniform dispatch, NJ=ceil(w/8)
        case 0: dmv_step<1>(w, cd, gid, lg, sI, sF, goNCl, goHMl, stHCl, stNCl, th_s, trans_param); break;
        case 1: dmv_step<2>(w, cd, gid, lg, sI, sF, goNCl, goHMl, stHCl, stNCl, th_s, trans_param); break;
        case 2: dmv_step<3>(w, cd, gid, lg, sI, sF, goNCl, goHMl, stHCl, stNCl, th_s, trans_param); break;
        case 3: dmv_step<4>(w, cd, gid, lg, sI, sF, goNCl, goHMl, stHCl, stNCl, th_s, trans_param); break;
        case 4: dmv_step<5>(w, cd, gid, lg, sI, sF, goNCl, goHMl, stHCl, stNCl, th_s, trans_param); break;
        case 5: dmv_step<6>(w, cd, gid, lg, sI, sF, goNCl, goHMl, stHCl, stNCl, th_s, trans_param); break;
        case 6: dmv_step<7>(w, cd, gid, lg, sI, sF, goNCl, goHMl, stHCl, stNCl, th_s, trans_param); break;
        default: dmv_step<8>(w, cd, gid, lg, sI, sF, goNCl, goHMl, stHCl, stNCl, th_s, trans_param); break;
        }
        __syncthreads();
    }

    // ---- final (linear): out = ln2*(log2( sum_i root_l*FL''*FR'' ) - ALPHA*last)
    if (tid < 64) {
        const int last = nl - 1;
        float fl0 = (tid == 0)    ? stNCl[0 * NMAX + 0]    : sF[tid * LDS_S + 0];
        float fre = (tid == last) ? stNCl[1 * NMAX + last] : sF[tid * LDS_S + last];
        float xx  = (tid < nl) ? (root_l[tid] * fl0 * fre) : 0.f;  // select kills NaN
        #pragma unroll
        for (int off = 1; off < 64; off <<= 1)
            xx += __shfl_xor(xx, off, 64);
        if (tid == 0) out[b] = (LOG2F(xx) - ALPHA * last) * LN2;
    }
}

extern "C" void kernel_launch(void* const* d_in, const int* in_sizes, int n_in,
                              void* d_out, int out_size, void* d_ws, size_t ws_size,
                              hipStream_t stream) {
    // setup_inputs order: id_array, tag_array, len_array, root_param, trans_param, dec_param
    const int*   tag   = (const int*)d_in[1];
    const int*   len_a = (const int*)d_in[2];
    const float* root  = (const float*)d_in[3];
    const float* trans = (const float*)d_in[4];
    const float* dec   = (const float*)d_in[5];
    float* outp = (float*)d_out;
    const int B = in_sizes[2];   // 1024

    int* blk2item = (int*)d_ws;  // B ints

    int sortThreads = (B < 1024) ? ((B + 63) & ~63) : 1024;
    if (sortThreads < 64) sortThreads = 64;
    order_kernel<<<1, sortThreads, 0, stream>>>(len_a, blk2item, B);
    dmv_inside_kernel<<<B, BLOCK, 0, stream>>>(tag, len_a, root, trans, dec,
                                               blk2item, outp);
}